// Round 5
// baseline (558.332 us; speedup 1.0000x reference)
//
#include <hip/hip_runtime.h>
#include <math.h>

// B=4, O=8, C=256, HID=128, H=W=64, STEPS=2
// fp16 MFMA implicit-GEMM conv, weights register-resident per 32-ci chunk.
//   enc:  relu(conv(feats,Wf) [ci-split partials] + conv(mask,Wm) + b)
//   gcn:  relu(conv(s_i, W1-W2) [raw] + conv(Sum, W2) + b)  -- one 36-image dispatch
//   ro :  sigmoid(conv(feats,Wa) + conv(s,Wb) + b)
// Activations fp16 HWC [img][px][ci]; weights pre-packed fp16 [tap][cout][cin].

typedef unsigned short ushort_t;
typedef _Float16 f16x8 __attribute__((ext_vector_type(8)));
typedef float f32x4 __attribute__((ext_vector_type(4)));

__device__ __forceinline__ ushort_t f2h(float f) {
    _Float16 h = (_Float16)f;
    return *(ushort_t*)&h;
}
__device__ __forceinline__ float h2f(ushort_t u) {
    _Float16 h = *(_Float16*)&u;
    return (float)h;
}

// ---- weight packing: WencF[9][128][256], WgcnS[9][128][128], WgcnD[9][128][128]
__global__ __launch_bounds__(256) void prep_weights(
    const float* __restrict__ enc_w, const float* __restrict__ gcn_w,
    ushort_t* __restrict__ WencF, ushort_t* __restrict__ WgcnS, ushort_t* __restrict__ WgcnD)
{
    int i = blockIdx.x * 256 + threadIdx.x;
    if (i < 294912) {                       // enc feats part: [t][co][ci<256]
        int t = i / 32768; int r = i & 32767; int co = r >> 8; int ci = r & 255;
        WencF[i] = f2h(enc_w[(co * 257 + ci) * 9 + t]);
    } else if (i < 442368) {                // gcn shared part W2
        int j = i - 294912; int t = j / 16384; int r = j & 16383; int co = r >> 7; int ci = r & 127;
        WgcnS[j] = f2h(gcn_w[(co * 256 + 128 + ci) * 9 + t]);
    } else if (i < 589824) {                // gcn diff W1-W2
        int j = i - 442368; int t = j / 16384; int r = j & 16383; int co = r >> 7; int ci = r & 127;
        WgcnD[j] = f2h(gcn_w[(co * 256 + ci) * 9 + t] - gcn_w[(co * 256 + 128 + ci) * 9 + t]);
    }
}

// ---- feats fp32 CHW -> fp16 HWC  [4][4096][256]
__global__ __launch_bounds__(256) void feats_to_hwc(const float* __restrict__ feats,
                                                    ushort_t* __restrict__ featsT)
{
    __shared__ float tile[64][65];
    int img = blockIdx.z, ct = blockIdx.y, pt = blockIdx.x;
    int t = threadIdx.x;
    int px_l = t & 63;
    const float* src = feats + ((size_t)img * 256 + ct * 64) * 4096 + pt * 64;
#pragma unroll
    for (int j = 0; j < 16; ++j) {
        int ci_l = (t >> 6) + j * 4;
        tile[px_l][ci_l] = src[(size_t)ci_l * 4096 + px_l];
    }
    __syncthreads();
    int px = t >> 2;
#pragma unroll
    for (int j = 0; j < 2; ++j) {
        int c8 = ((t & 3) + j * 4) * 8;
        uint4 v; ushort_t* pv = (ushort_t*)&v;
#pragma unroll
        for (int k = 0; k < 8; ++k) pv[k] = f2h(tile[px][c8 + k]);
        *(uint4*)(featsT + ((size_t)img * 4096 + pt * 64 + px) * 256 + ct * 64 + c8) = v;
    }
}

// ---- fused MFMA conv (raw outputs, no bias/relu here)
// grid: (32 row-pairs, nA+nB images, ci-chunks). Block: 128 co x 128 px, 4 waves
// as (cg,pg) in {0,1}^2: wave = 64 couts x 64 px (one row). cin slice = 128
// (4 LDS chunks of 32 ci). Weights for the chunk live in 144 VGPRs per wave.
// img < nA:  x=xA[img], W=WA, fp16 raw -> outA[img]
// img >= nA: x=xB[img-nA], W=WB, fp32 raw -> outB[zc*nB + img-nA]
__global__ __launch_bounds__(256, 2) void conv_mfma(
    const ushort_t* __restrict__ xA, const ushort_t* __restrict__ WA,
    ushort_t* __restrict__ outA, int nA,
    const ushort_t* __restrict__ xB, const ushort_t* __restrict__ WB,
    float* __restrict__ outB, int nB, int cin_total)
{
    __shared__ uint4 raw[1320];               // 21120 B: xs[4][66][40] fp16 / epilogue buf
    ushort_t* xs = (ushort_t*)raw;
    ushort_t* eb16 = (ushort_t*)raw;          // [64][136] fp16 epilogue
    float* eb32 = (float*)raw;                // [64][68] fp32 epilogue

    const int rp = blockIdx.x, img = blockIdx.y, zc = blockIdx.z;
    const int row0 = rp * 2;
    const int ci0 = zc * 128;
    const int tid = threadIdx.x;
    const int w = tid >> 6, lane = tid & 63, lq = lane >> 4, lr = lane & 15;
    const int cg = w >> 1, pg = w & 1;        // co-half, px-row

    const bool isA = img < nA;
    const ushort_t* x = isA ? xA + (size_t)img * 4096 * cin_total
                            : xB + (size_t)(img - nA) * 4096 * cin_total;
    const ushort_t* W = isA ? WA : WB;

    f32x4 acc[4][4];                          // [co-tile][px-tile]
#pragma unroll
    for (int a = 0; a < 4; ++a)
#pragma unroll
        for (int p = 0; p < 4; ++p) acc[a][p] = (f32x4){0.f, 0.f, 0.f, 0.f};

#pragma unroll
    for (int cc = 0; cc < 4; ++cc) {
        const int cib = ci0 + cc * 32;
        __syncthreads();                      // prev chunk's LDS reads done

        // issue this chunk's weights into registers (overlaps act staging)
        f16x8 wreg[9][4];
#pragma unroll
        for (int t = 0; t < 9; ++t)
#pragma unroll
            for (int ct = 0; ct < 4; ++ct)
                wreg[t][ct] = *(const f16x8*)(
                    W + (size_t)(t * 128 + cg * 64 + ct * 16 + lr) * cin_total + cib + lq * 8);

        // stage acts: rows row0-1..row0+2, cols -1..64, 32 ci (as 4x 16B)
        for (int i = tid; i < 1056; i += 256) {
            int r = i / 264, rem = i - r * 264;
            int c = rem >> 2, s = rem & 3;
            int gy = row0 - 1 + r, gx = c - 1;
            uint4 v = make_uint4(0, 0, 0, 0);
            if ((unsigned)gy < 64u && (unsigned)gx < 64u)
                v = *(const uint4*)(x + (size_t)(gy * 64 + gx) * cin_total + cib + s * 8);
            *(uint4*)(xs + (r * 66 + c) * 40 + s * 8) = v;
        }
        __syncthreads();

#pragma unroll
        for (int t = 0; t < 9; ++t) {
            const int dy = t / 3, dx = t - dy * 3;
            const ushort_t* bb = xs + ((pg + dy) * 66 + dx + lr) * 40 + lq * 8;
#pragma unroll
            for (int p = 0; p < 4; ++p) {
                f16x8 b = *(const f16x8*)(bb + p * 640);     // p*16*40
                acc[0][p] = __builtin_amdgcn_mfma_f32_16x16x32_f16(wreg[t][0], b, acc[0][p], 0, 0, 0);
                acc[1][p] = __builtin_amdgcn_mfma_f32_16x16x32_f16(wreg[t][1], b, acc[1][p], 0, 0, 0);
                acc[2][p] = __builtin_amdgcn_mfma_f32_16x16x32_f16(wreg[t][2], b, acc[2][p], 0, 0, 0);
                acc[3][p] = __builtin_amdgcn_mfma_f32_16x16x32_f16(wreg[t][3], b, acc[3][p], 0, 0, 0);
            }
        }
    }

    // ---- epilogue: raw stores via LDS transpose
    if (isA) {
        ushort_t* oimg = outA + (size_t)img * 4096 * 128;
#pragma unroll
        for (int r = 0; r < 2; ++r) {
            __syncthreads();
            if (pg == r) {
#pragma unroll
                for (int ct = 0; ct < 4; ++ct)
#pragma unroll
                    for (int p = 0; p < 4; ++p) {
                        ushort_t pk[4];
#pragma unroll
                        for (int j = 0; j < 4; ++j) pk[j] = f2h(acc[ct][p][j]);
                        *(uint2*)(eb16 + (p * 16 + lr) * 136 + cg * 64 + ct * 16 + lq * 4) =
                            *(uint2*)pk;
                    }
            }
            __syncthreads();
#pragma unroll
            for (int k = 0; k < 4; ++k) {
                int i = tid + k * 256;
                int px = i >> 4, c16 = i & 15;
                uint4 v = *(uint4*)(eb16 + px * 136 + c16 * 8);
                *(uint4*)(oimg + ((size_t)(row0 + r) * 64 + px) * 128 + c16 * 8) = v;
            }
        }
    } else {
        float* oimg = outB + ((size_t)zc * nB + (img - nA)) * 4096 * 128;
#pragma unroll
        for (int r = 0; r < 2; ++r)
#pragma unroll
            for (int h = 0; h < 2; ++h) {
                __syncthreads();
                if (pg == r && cg == h) {
#pragma unroll
                    for (int ct = 0; ct < 4; ++ct)
#pragma unroll
                        for (int p = 0; p < 4; ++p)
                            *(f32x4*)(eb32 + (p * 16 + lr) * 68 + ct * 16 + lq * 4) = acc[ct][p];
                }
                __syncthreads();
                for (int i = tid; i < 512; i += 256) {
                    int px = i >> 3, cl = (i & 7) * 8;
                    f32x4 v0 = *(f32x4*)(eb32 + px * 68 + cl);
                    f32x4 v1 = *(f32x4*)(eb32 + px * 68 + cl + 4);
                    float* op = oimg + ((size_t)(row0 + r) * 64 + px) * 128 + h * 64 + cl;
                    *(f32x4*)op = v0;
                    *(f32x4*)(op + 4) = v1;
                }
            }
    }
}

// ---- gcn combine: S = relu(S_raw + U2[b] + gcn_b), USum = sum_o S  (fp32 math)
__global__ __launch_bounds__(256) void combine_sum(
    ushort_t* __restrict__ S, const float* __restrict__ U2,
    const float* __restrict__ gcn_b, ushort_t* __restrict__ USum)
{
    int i = blockIdx.x * 256 + threadIdx.x;   // b(2)|px(12)|c16(4)
    int c8 = (i & 15) << 3, px = (i >> 4) & 4095, b = i >> 16;
    const float* u = U2 + ((size_t)b * 4096 + px) * 128 + c8;
    float base[8];
#pragma unroll
    for (int k = 0; k < 8; ++k) base[k] = u[k] + gcn_b[c8 + k];
    float s[8] = {0, 0, 0, 0, 0, 0, 0, 0};
#pragma unroll
    for (int o = 0; o < 8; ++o) {
        ushort_t* p = S + ((size_t)(b * 8 + o) * 4096 + px) * 128 + c8;
        uint4 v = *(uint4*)p;
        ushort_t* vp = (ushort_t*)&v;
        uint4 sv; ushort_t* sp = (ushort_t*)&sv;
#pragma unroll
        for (int k = 0; k < 8; ++k) {
            float f = fmaxf(h2f(vp[k]) + base[k], 0.f);
            s[k] += f;
            sp[k] = f2h(f);
        }
        *(uint4*)p = sv;
    }
    uint4 sv; ushort_t* sp = (ushort_t*)&sv;
#pragma unroll
    for (int k = 0; k < 8; ++k) sp[k] = f2h(s[k]);
    *(uint4*)(USum + ((size_t)b * 4096 + px) * 128 + c8) = sv;
}

// ---- encoder per-object part + object-sum:
// S = relu(U1p0 + U1p1 + enc_b + conv3x3(mask_o, Wm)), USum = sum_o S
__global__ __launch_bounds__(256) void enc_obj_sum(
    const float* __restrict__ masks, const float* __restrict__ enc_w,
    const float* __restrict__ enc_b, const float* __restrict__ U1p,
    ushort_t* __restrict__ S, ushort_t* __restrict__ USum)
{
    int i = blockIdx.x * 256 + threadIdx.x;   // b(2)|px(12)|c16(4)
    int c8 = (i & 15) << 3, px = (i >> 4) & 4095, b = i >> 16;
    int y = px >> 6, xx = px & 63;
    const float* p0 = U1p + ((size_t)b * 4096 + px) * 128 + c8;
    const float* p1 = p0 + 2097152;           // second ci-half partial
    float base[8];
#pragma unroll
    for (int k = 0; k < 8; ++k) base[k] = p0[k] + p1[k] + enc_b[c8 + k];
    float wm[8][9];
#pragma unroll
    for (int k = 0; k < 8; ++k) {
        const float* wp = enc_w + (size_t)((c8 + k) * 257 + 256) * 9;
#pragma unroll
        for (int t = 0; t < 9; ++t) wm[k][t] = wp[t];
    }
    float s[8] = {0, 0, 0, 0, 0, 0, 0, 0};
#pragma unroll
    for (int o = 0; o < 8; ++o) {
        const float* m = masks + (size_t)(b * 8 + o) * 4096;
        float mt[9];
#pragma unroll
        for (int dy = 0; dy < 3; ++dy)
#pragma unroll
            for (int dx = 0; dx < 3; ++dx) {
                int gy = y + dy - 1, gx = xx + dx - 1;
                mt[dy * 3 + dx] =
                    ((unsigned)gy < 64u && (unsigned)gx < 64u) ? m[gy * 64 + gx] : 0.f;
            }
        uint4 sv; ushort_t* sp = (ushort_t*)&sv;
#pragma unroll
        for (int k = 0; k < 8; ++k) {
            float acc = base[k];
#pragma unroll
            for (int t = 0; t < 9; ++t) acc = fmaf(mt[t], wm[k][t], acc);
            acc = fmaxf(acc, 0.f);
            s[k] += acc;
            sp[k] = f2h(acc);
        }
        *(uint4*)(S + ((size_t)(b * 8 + o) * 4096 + px) * 128 + c8) = sv;
    }
    uint4 sv; ushort_t* sp = (ushort_t*)&sv;
#pragma unroll
    for (int k = 0; k < 8; ++k) sp[k] = f2h(s[k]);
    *(uint4*)(USum + ((size_t)b * 4096 + px) * 128 + c8) = sv;
}

// ---- readout shared part (fp32 feats CHW), split over ci-chunks + atomicAdd
__global__ __launch_bounds__(256) void ro_shared(const float* __restrict__ feats,
                                                 const float* __restrict__ ro_w,
                                                 float* __restrict__ YR)
{
    int i = blockIdx.x * 256 + threadIdx.x;   // b(2)|chunk(3)|px(12)
    int px = i & 4095, chunk = (i >> 12) & 7, b = i >> 15;
    int y = px >> 6, xx = px & 63;
    const float* xb = feats + ((size_t)b * 256 + chunk * 32) * 4096;
    float acc = 0.f;
    for (int ci = 0; ci < 32; ++ci) {
        const float* xp = xb + (size_t)ci * 4096;
        const float* wp = ro_w + (chunk * 32 + ci) * 9;
#pragma unroll
        for (int dy = 0; dy < 3; ++dy) {
            int gy = y + dy - 1;
            if ((unsigned)gy >= 64u) continue;
#pragma unroll
            for (int dx = 0; dx < 3; ++dx) {
                int gx = xx + dx - 1;
                if ((unsigned)gx >= 64u) continue;
                acc = fmaf(wp[dy * 3 + dx], xp[gy * 64 + gx], acc);
            }
        }
    }
    atomicAdd(&YR[b * 4096 + px], acc);
}

// ---- readout per-object part (fp16 HWC states) + sigmoid
__global__ __launch_bounds__(256) void ro_obj(
    const ushort_t* __restrict__ S, const float* __restrict__ ro_w,
    const float* __restrict__ ro_b, const float* __restrict__ YR,
    float* __restrict__ out)
{
    int i = blockIdx.x * 256 + threadIdx.x;   // n(5)|px(12)
    int px = i & 4095, n = i >> 12;
    int b = n >> 3, y = px >> 6, xx = px & 63;
    float a[4];
    a[0] = YR[b * 4096 + px] + ro_b[0]; a[1] = 0.f; a[2] = 0.f; a[3] = 0.f;
    const ushort_t* sb = S + (size_t)n * 524288;
    const float* wb = ro_w + 256 * 9;
    for (int dy = 0; dy < 3; ++dy) {
        int gy = y + dy - 1;
        if ((unsigned)gy >= 64u) continue;
        for (int dx = 0; dx < 3; ++dx) {
            int gx = xx + dx - 1;
            if ((unsigned)gx >= 64u) continue;
            const ushort_t* sp = sb + (size_t)(gy * 64 + gx) * 128;
            const float* wp = wb + dy * 3 + dx;
#pragma unroll
            for (int c8 = 0; c8 < 16; ++c8) {
                uint4 v = *(const uint4*)(sp + c8 * 8);
                const ushort_t* vp = (const ushort_t*)&v;
#pragma unroll
                for (int k = 0; k < 8; ++k)
                    a[c8 & 3] = fmaf(h2f(vp[k]), wp[(c8 * 8 + k) * 9], a[c8 & 3]);
            }
        }
    }
    float acc = (a[0] + a[1]) + (a[2] + a[3]);
    out[i] = 1.f / (1.f + __expf(-acc));
}

extern "C" void kernel_launch(void* const* d_in, const int* in_sizes, int n_in,
                              void* d_out, int out_size, void* d_ws, size_t ws_size,
                              hipStream_t stream)
{
    const float* feats = (const float*)d_in[0];   // [4,256,64,64]
    const float* masks = (const float*)d_in[1];   // [4,8,64,64]
    const float* enc_w = (const float*)d_in[4];   // [128,257,3,3]
    const float* enc_b = (const float*)d_in[5];
    const float* gcn_w = (const float*)d_in[6];   // [128,256,3,3]
    const float* gcn_b = (const float*)d_in[7];
    const float* ro_w  = (const float*)d_in[8];   // [1,384,3,3]
    const float* ro_b  = (const float*)d_in[9];
    float* out = (float*)d_out;                   // [4,8,64,64]

    // workspace: fp16 region then fp32 region (all 16B-aligned)
    ushort_t* WencF  = (ushort_t*)d_ws;           // 294912
    ushort_t* WgcnS  = WencF + 294912;            // 147456
    ushort_t* WgcnD  = WgcnS + 147456;            // 147456
    ushort_t* featsT = WgcnD + 147456;            // 4*4096*256
    ushort_t* Sa     = featsT + 4194304;          // 32*4096*128
    ushort_t* Sb     = Sa + 16777216;             // 32*4096*128
    ushort_t* USum   = Sb + 16777216;             // 4*4096*128
    float*    U1p    = (float*)(USum + 2097152);  // [2][4][4096][128] fp32
    float*    U2     = U1p + 4194304;             // [4][4096][128] fp32
    float*    YR     = U2 + 2097152;              // 4*4096 fp32

    dim3 blk(256);

    hipMemsetAsync(YR, 0, 4 * 4096 * sizeof(float), stream);
    prep_weights<<<2304, blk, 0, stream>>>(enc_w, gcn_w, WencF, WgcnS, WgcnD);
    feats_to_hwc<<<dim3(64, 4, 4), blk, 0, stream>>>(feats, featsT);

    // encoder shared conv, ci-split into 2 partials (z = ci-half)
    conv_mfma<<<dim3(32, 4, 2), blk, 0, stream>>>(
        nullptr, nullptr, nullptr, 0, featsT, WencF, U1p, 4, 256);
    enc_obj_sum<<<1024, blk, 0, stream>>>(masks, enc_w, enc_b, U1p, Sa, USum);

    // 2 message-passing steps, fused 36-image conv + combine
    conv_mfma<<<dim3(32, 36, 1), blk, 0, stream>>>(
        Sa, WgcnD, Sb, 32, USum, WgcnS, U2, 4, 128);
    combine_sum<<<1024, blk, 0, stream>>>(Sb, U2, gcn_b, USum);

    conv_mfma<<<dim3(32, 36, 1), blk, 0, stream>>>(
        Sb, WgcnD, Sa, 32, USum, WgcnS, U2, 4, 128);
    combine_sum<<<1024, blk, 0, stream>>>(Sa, U2, gcn_b, USum);

    // readout (final states in Sa)
    ro_shared<<<512, blk, 0, stream>>>(feats, ro_w, YR);
    ro_obj<<<512, blk, 0, stream>>>(Sa, ro_w, ro_b, YR, out);
}

// Round 6
// 309.308 us; speedup vs baseline: 1.8051x; 1.8051x over previous
//
#include <hip/hip_runtime.h>
#include <math.h>

// B=4, O=8, C=256, HID=128, H=W=64, STEPS=2
// m97-style MFMA conv: both operands staged to LDS via global_load_lds (16B),
// double-buffered, 1 barrier/chunk, prefetch in flight across the barrier.
// Activations in ci-chunked HWC: act[img][cc][px][ci32] (cc=ci/32) so every
// (row, cc) slab is 4KB contiguous (DMA-able). Weights packed [t][cc][co][ci32]
// (8KB contiguous slabs).
//   enc:  relu(conv(feats,Wf) [4 ci-quad partials] + conv(mask,Wm) + b)
//   gcn:  relu(conv(s_i,W1-W2) [raw] + conv(Sum,W2) + b)  -- one 36-img dispatch
//   ro :  sigmoid(conv(feats,Wa) + conv(s,Wb) + b)

typedef unsigned short ushort_t;
typedef _Float16 f16x8 __attribute__((ext_vector_type(8)));
typedef float f32x4 __attribute__((ext_vector_type(4)));

#define GLDS(gsrc, ldst)                                                      \
    __builtin_amdgcn_global_load_lds(                                         \
        (const __attribute__((address_space(1))) unsigned int*)(gsrc),        \
        (__attribute__((address_space(3))) unsigned int*)(ldst), 16, 0, 0)

__device__ __forceinline__ ushort_t f2h(float f) {
    _Float16 h = (_Float16)f;
    return *(ushort_t*)&h;
}
__device__ __forceinline__ float h2f(ushort_t u) {
    _Float16 h = *(_Float16*)&u;
    return (float)h;
}

// ---- weight packing: WencF[t][cc8][co128][ci32], WgcnS/D[t][cc4][co128][ci32]
__global__ __launch_bounds__(256) void prep_weights(
    const float* __restrict__ enc_w, const float* __restrict__ gcn_w,
    ushort_t* __restrict__ WencF, ushort_t* __restrict__ WgcnS, ushort_t* __restrict__ WgcnD)
{
    int i = blockIdx.x * 256 + threadIdx.x;
    if (i < 294912) {
        int ci32 = i & 31, co = (i >> 5) & 127, tc = i >> 12;   // tc = t*8+cc
        int t = tc >> 3, cc = tc & 7, ci = cc * 32 + ci32;
        WencF[i] = f2h(enc_w[(co * 257 + ci) * 9 + t]);
    } else if (i < 442368) {
        int j = i - 294912;
        int ci32 = j & 31, co = (j >> 5) & 127, tc = j >> 12;   // t*4+cc
        int t = tc >> 2, cc = tc & 3, ci = cc * 32 + ci32;
        WgcnS[j] = f2h(gcn_w[(co * 256 + 128 + ci) * 9 + t]);
    } else if (i < 589824) {
        int j = i - 442368;
        int ci32 = j & 31, co = (j >> 5) & 127, tc = j >> 12;
        int t = tc >> 2, cc = tc & 3, ci = cc * 32 + ci32;
        WgcnD[j] = f2h(gcn_w[(co * 256 + ci) * 9 + t] - gcn_w[(co * 256 + 128 + ci) * 9 + t]);
    }
}

// ---- feats fp32 CHW -> fp16 chunked HWC [4][cc8][4096][32]
__global__ __launch_bounds__(256) void feats_to_hwc(const float* __restrict__ feats,
                                                    ushort_t* __restrict__ featsT)
{
    __shared__ float tile[64][65];
    int img = blockIdx.z, ct = blockIdx.y, pt = blockIdx.x;   // ct = 64-ci block
    int t = threadIdx.x;
    int px_l = t & 63;
    const float* src = feats + ((size_t)img * 256 + ct * 64) * 4096 + pt * 64;
#pragma unroll
    for (int j = 0; j < 16; ++j) {
        int ci_l = (t >> 6) + j * 4;
        tile[px_l][ci_l] = src[(size_t)ci_l * 4096 + px_l];
    }
    __syncthreads();
    int px = t >> 2;
#pragma unroll
    for (int j = 0; j < 2; ++j) {
        int c8 = ((t & 3) + j * 4) * 8;                       // 0..56 within 64-ci block
        uint4 v; ushort_t* pv = (ushort_t*)&v;
#pragma unroll
        for (int k = 0; k < 8; ++k) pv[k] = f2h(tile[px][c8 + k]);
        int cc = ct * 2 + (c8 >> 5);
        *(uint4*)(featsT + ((size_t)img * 8 + cc) * 131072 +
                  (size_t)(pt * 64 + px) * 32 + (c8 & 31)) = v;
    }
}

// ---- main conv. grid (32 rowpairs, nA+nB imgs, kz). block 256, 4 waves.
// Block tile: 128 co x 128 px (2 rows). Wave (cg,pg): 64 co x 64 px.
// K-loop: ncc_blk ci-chunks x 9 taps; acts staged per cc (4 rows, dbuf),
// weights streamed per chunk (8KB, dbuf), all via global_load_lds.
__global__ __launch_bounds__(256, 3) void conv_mfma(
    const ushort_t* __restrict__ xA, const ushort_t* __restrict__ WA,
    ushort_t* __restrict__ outA, int nA,
    const ushort_t* __restrict__ xB, const ushort_t* __restrict__ WB,
    float* __restrict__ outB, int nB,
    int ncc_img, int ncc_blk)
{
    __shared__ ushort_t raw[25088];           // 50176 B
    ushort_t* xs = raw;                       // 2 x [4 rows][66 cols][32ci] = 2 x 8448
    ushort_t* wlds = raw + 16896;             // 2 x [128 co][32ci] = 2 x 4096
    ushort_t* eb16 = raw;                     // epilogue overlay [64][136]
    float* eb32 = (float*)raw;                // epilogue overlay [64][68]

    const int rp = blockIdx.x, img = blockIdx.y, kz = blockIdx.z;
    const int row0 = rp * 2;
    const int cc0 = kz * ncc_blk;
    const int nchunk = 9 * ncc_blk;
    const int tid = threadIdx.x;
    const int w = tid >> 6, lane = tid & 63, lq = lane >> 4, lr = lane & 15;
    const int cg = w >> 1, pg = w & 1;

    const bool isA = img < nA;
    const ushort_t* x = isA ? xA + (size_t)img * ncc_img * 131072
                            : xB + (size_t)(img - nA) * ncc_img * 131072;
    const ushort_t* W = isA ? WA : WB;

    // zero the halo columns (col 0 and 65) of both act buffers, once
    if (tid < 64) {
        int b = tid >> 5, r = (tid >> 3) & 3, c = (tid >> 2) & 1, s = tid & 3;
        *(uint4*)(xs + b * 8448 + r * 2112 + (c ? 65 : 0) * 32 + s * 8) =
            make_uint4(0, 0, 0, 0);
    }

    f32x4 acc[4][4];
#pragma unroll
    for (int a = 0; a < 4; ++a)
#pragma unroll
        for (int p = 0; p < 4; ++p) acc[a][p] = (f32x4){0.f, 0.f, 0.f, 0.f};

    // stage helpers (each wave stages one act row / 2 weight segments)
    const int gy = row0 - 1 + w;
    const bool row_ok = (unsigned)gy < 64u;
#define STAGE_ACT(cc_, buf_)                                                    \
    {                                                                           \
        ushort_t* dst = xs + (buf_) * 8448 + w * 2112 + 32;                     \
        if (row_ok) {                                                           \
            const ushort_t* src = x + (size_t)(cc_) * 131072 + (size_t)gy * 2048; \
            GLDS(src + 0 * 512 + lane * 8, dst + 0 * 512);                      \
            GLDS(src + 1 * 512 + lane * 8, dst + 1 * 512);                      \
            GLDS(src + 2 * 512 + lane * 8, dst + 2 * 512);                      \
            GLDS(src + 3 * 512 + lane * 8, dst + 3 * 512);                      \
        } else {                                                                \
            *(uint4*)(dst + 0 * 512 + lane * 8) = make_uint4(0, 0, 0, 0);       \
            *(uint4*)(dst + 1 * 512 + lane * 8) = make_uint4(0, 0, 0, 0);       \
            *(uint4*)(dst + 2 * 512 + lane * 8) = make_uint4(0, 0, 0, 0);       \
            *(uint4*)(dst + 3 * 512 + lane * 8) = make_uint4(0, 0, 0, 0);       \
        }                                                                       \
    }
#define STAGE_W(t_, cc_, buf_)                                                  \
    {                                                                           \
        const ushort_t* src = W + ((size_t)((t_) * ncc_img + (cc_)) * 4096);    \
        ushort_t* dst = wlds + (buf_) * 4096;                                   \
        GLDS(src + (w * 2 + 0) * 512 + lane * 8, dst + (w * 2 + 0) * 512);      \
        GLDS(src + (w * 2 + 1) * 512 + lane * 8, dst + (w * 2 + 1) * 512);      \
    }

    STAGE_ACT(cc0, 0);
    STAGE_W(0, cc0, 0);

    int kc = 0;
    for (int ccl = 0; ccl < ncc_blk; ++ccl) {
        const int cc = cc0 + ccl;
        const int xb = ccl & 1;
#pragma unroll
        for (int t = 0; t < 9; ++t, ++kc) {
            __syncthreads();                  // drains glds(kc) (in flight 1 chunk)
            if (kc + 1 < nchunk) {
                if (t == 8) {
                    STAGE_W(0, cc + 1, (kc + 1) & 1);
                    STAGE_ACT(cc + 1, (ccl + 1) & 1);
                } else {
                    STAGE_W(t + 1, cc, (kc + 1) & 1);
                }
            }
            const int dy = t / 3, dx = t - 3 * dy;
            const ushort_t* wl = wlds + (kc & 1) * 4096 + (cg * 64 + lr) * 32 + lq * 8;
            const ushort_t* xl = xs + xb * 8448 + (pg + dy) * 2112 + (dx + lr) * 32 + lq * 8;
            f16x8 A0 = *(const f16x8*)(wl);
            f16x8 A1 = *(const f16x8*)(wl + 512);    // +16 co
            f16x8 A2 = *(const f16x8*)(wl + 1024);
            f16x8 A3 = *(const f16x8*)(wl + 1536);
#pragma unroll
            for (int p = 0; p < 4; ++p) {
                f16x8 Bf = *(const f16x8*)(xl + p * 512);   // +16 px
                acc[0][p] = __builtin_amdgcn_mfma_f32_16x16x32_f16(A0, Bf, acc[0][p], 0, 0, 0);
                acc[1][p] = __builtin_amdgcn_mfma_f32_16x16x32_f16(A1, Bf, acc[1][p], 0, 0, 0);
                acc[2][p] = __builtin_amdgcn_mfma_f32_16x16x32_f16(A2, Bf, acc[2][p], 0, 0, 0);
                acc[3][p] = __builtin_amdgcn_mfma_f32_16x16x32_f16(A3, Bf, acc[3][p], 0, 0, 0);
            }
        }
    }

    // ---- epilogue (raw, no bias/relu). A: fp16 chunked. B: fp32 [px][128].
    if (isA) {
        ushort_t* obase = outA + (size_t)img * ncc_img * 131072;
#pragma unroll
        for (int r = 0; r < 2; ++r) {
            __syncthreads();
            if (pg == r) {
#pragma unroll
                for (int cf = 0; cf < 4; ++cf)
#pragma unroll
                    for (int pf = 0; pf < 4; ++pf) {
                        int px = pf * 16 + lr;
                        int co_l = cg * 64 + cf * 16 + lq * 4;
                        ushort_t pk[4];
#pragma unroll
                        for (int j = 0; j < 4; ++j) pk[j] = f2h(acc[cf][pf][j]);
                        *(uint2*)(eb16 + px * 136 + co_l) = *(uint2*)pk;
                    }
            }
            __syncthreads();
#pragma unroll
            for (int k = 0; k < 4; ++k) {
                int i = tid + k * 256;
                int px = i >> 4, c16 = i & 15;
                uint4 v = *(uint4*)(eb16 + px * 136 + c16 * 8);
                *(uint4*)(obase + (size_t)(c16 >> 2) * 131072 +
                          (size_t)((row0 + r) * 64 + px) * 32 + (c16 & 3) * 8) = v;
            }
        }
    } else {
        float* obase = outB + ((size_t)kz * nB + (img - nA)) * 524288;
#pragma unroll
        for (int r = 0; r < 2; ++r)
#pragma unroll
            for (int h = 0; h < 2; ++h) {
                __syncthreads();
                if (pg == r && cg == h) {
#pragma unroll
                    for (int cf = 0; cf < 4; ++cf)
#pragma unroll
                        for (int pf = 0; pf < 4; ++pf)
                            *(f32x4*)(eb32 + (pf * 16 + lr) * 68 + cf * 16 + lq * 4) =
                                acc[cf][pf];
                }
                __syncthreads();
                for (int i = tid; i < 512; i += 256) {
                    int px = i >> 3, cl = (i & 7) * 8;
                    f32x4 v0 = *(f32x4*)(eb32 + px * 68 + cl);
                    f32x4 v1 = *(f32x4*)(eb32 + px * 68 + cl + 4);
                    float* op = obase + (size_t)((row0 + r) * 64 + px) * 128 + h * 64 + cl;
                    *(f32x4*)op = v0;
                    *(f32x4*)(op + 4) = v1;
                }
            }
    }
#undef STAGE_ACT
#undef STAGE_W
}

// ---- gcn combine: S = relu(S_raw + U2[b] + gcn_b), USum = sum_o S (chunked io)
__global__ __launch_bounds__(256) void combine_sum(
    ushort_t* __restrict__ S, const float* __restrict__ U2,
    const float* __restrict__ gcn_b, ushort_t* __restrict__ USum)
{
    int i = blockIdx.x * 256 + threadIdx.x;   // b(2)|px(12)|c16(4)
    int c8 = i & 15, px = (i >> 4) & 4095, b = i >> 16;
    int co = c8 * 8;
    size_t coff = (size_t)(c8 >> 2) * 131072 + (size_t)px * 32 + (c8 & 3) * 8;
    const float* u = U2 + ((size_t)b * 4096 + px) * 128 + co;
    float base[8];
#pragma unroll
    for (int k = 0; k < 8; ++k) base[k] = u[k] + gcn_b[co + k];
    float s[8] = {0, 0, 0, 0, 0, 0, 0, 0};
#pragma unroll
    for (int o = 0; o < 8; ++o) {
        ushort_t* p = S + (size_t)(b * 8 + o) * 524288 + coff;
        uint4 v = *(uint4*)p;
        ushort_t* vp = (ushort_t*)&v;
        uint4 sv; ushort_t* sp = (ushort_t*)&sv;
#pragma unroll
        for (int k = 0; k < 8; ++k) {
            float f = fmaxf(h2f(vp[k]) + base[k], 0.f);
            s[k] += f;
            sp[k] = f2h(f);
        }
        *(uint4*)p = sv;
    }
    uint4 sv; ushort_t* sp = (ushort_t*)&sv;
#pragma unroll
    for (int k = 0; k < 8; ++k) sp[k] = f2h(s[k]);
    *(uint4*)(USum + (size_t)b * 524288 + coff) = sv;
}

// ---- encoder per-object part + object-sum (4 fp32 partials in, chunked out)
__global__ __launch_bounds__(256) void enc_obj_sum(
    const float* __restrict__ masks, const float* __restrict__ enc_w,
    const float* __restrict__ enc_b, const float* __restrict__ U1p,
    ushort_t* __restrict__ S, ushort_t* __restrict__ USum)
{
    int i = blockIdx.x * 256 + threadIdx.x;   // b(2)|px(12)|c16(4)
    int c8 = i & 15, px = (i >> 4) & 4095, b = i >> 16;
    int co = c8 * 8;
    int y = px >> 6, xx = px & 63;
    size_t coff = (size_t)(c8 >> 2) * 131072 + (size_t)px * 32 + (c8 & 3) * 8;
    const float* p0 = U1p + ((size_t)b * 4096 + px) * 128 + co;
    float base[8];
#pragma unroll
    for (int k = 0; k < 8; ++k)
        base[k] = ((p0[k] + p0[k + 2097152]) + (p0[k + 4194304] + p0[k + 6291456]))
                  + enc_b[co + k];
    float wm[8][9];
#pragma unroll
    for (int k = 0; k < 8; ++k) {
        const float* wp = enc_w + (size_t)((co + k) * 257 + 256) * 9;
#pragma unroll
        for (int t = 0; t < 9; ++t) wm[k][t] = wp[t];
    }
    float s[8] = {0, 0, 0, 0, 0, 0, 0, 0};
#pragma unroll
    for (int o = 0; o < 8; ++o) {
        const float* m = masks + (size_t)(b * 8 + o) * 4096;
        float mt[9];
#pragma unroll
        for (int dy = 0; dy < 3; ++dy)
#pragma unroll
            for (int dx = 0; dx < 3; ++dx) {
                int gy_ = y + dy - 1, gx = xx + dx - 1;
                mt[dy * 3 + dx] =
                    ((unsigned)gy_ < 64u && (unsigned)gx < 64u) ? m[gy_ * 64 + gx] : 0.f;
            }
        uint4 sv; ushort_t* sp = (ushort_t*)&sv;
#pragma unroll
        for (int k = 0; k < 8; ++k) {
            float acc = base[k];
#pragma unroll
            for (int t = 0; t < 9; ++t) acc = fmaf(mt[t], wm[k][t], acc);
            acc = fmaxf(acc, 0.f);
            s[k] += acc;
            sp[k] = f2h(acc);
        }
        *(uint4*)(S + (size_t)(b * 8 + o) * 524288 + coff) = sv;
    }
    uint4 sv; ushort_t* sp = (ushort_t*)&sv;
#pragma unroll
    for (int k = 0; k < 8; ++k) sp[k] = f2h(s[k]);
    *(uint4*)(USum + (size_t)b * 524288 + coff) = sv;
}

// ---- readout shared part (fp32 feats CHW), split over ci-chunks + atomicAdd
__global__ __launch_bounds__(256) void ro_shared(const float* __restrict__ feats,
                                                 const float* __restrict__ ro_w,
                                                 float* __restrict__ YR)
{
    int i = blockIdx.x * 256 + threadIdx.x;   // b(2)|chunk(3)|px(12)
    int px = i & 4095, chunk = (i >> 12) & 7, b = i >> 15;
    int y = px >> 6, xx = px & 63;
    const float* xb = feats + ((size_t)b * 256 + chunk * 32) * 4096;
    float acc = 0.f;
    for (int ci = 0; ci < 32; ++ci) {
        const float* xp = xb + (size_t)ci * 4096;
        const float* wp = ro_w + (chunk * 32 + ci) * 9;
#pragma unroll
        for (int dy = 0; dy < 3; ++dy) {
            int gy = y + dy - 1;
            if ((unsigned)gy >= 64u) continue;
#pragma unroll
            for (int dx = 0; dx < 3; ++dx) {
                int gx = xx + dx - 1;
                if ((unsigned)gx >= 64u) continue;
                acc = fmaf(wp[dy * 3 + dx], xp[gy * 64 + gx], acc);
            }
        }
    }
    atomicAdd(&YR[b * 4096 + px], acc);
}

// ---- readout per-object part (chunked fp16 states) + sigmoid
__global__ __launch_bounds__(256) void ro_obj(
    const ushort_t* __restrict__ S, const float* __restrict__ ro_w,
    const float* __restrict__ ro_b, const float* __restrict__ YR,
    float* __restrict__ out)
{
    int i = blockIdx.x * 256 + threadIdx.x;   // n(5)|px(12)
    int px = i & 4095, n = i >> 12;
    int b = n >> 3, y = px >> 6, xx = px & 63;
    float a[4];
    a[0] = YR[b * 4096 + px] + ro_b[0]; a[1] = 0.f; a[2] = 0.f; a[3] = 0.f;
    const ushort_t* sb = S + (size_t)n * 524288;
    const float* wb = ro_w + 256 * 9;
    for (int dy = 0; dy < 3; ++dy) {
        int gy = y + dy - 1;
        if ((unsigned)gy >= 64u) continue;
        for (int dx = 0; dx < 3; ++dx) {
            int gx = xx + dx - 1;
            if ((unsigned)gx >= 64u) continue;
            int p2 = gy * 64 + gx;
            const float* wp = wb + dy * 3 + dx;
#pragma unroll
            for (int cB = 0; cB < 4; ++cB) {
                const ushort_t* sp = sb + (size_t)cB * 131072 + (size_t)p2 * 32;
#pragma unroll
                for (int c4 = 0; c4 < 4; ++c4) {
                    uint4 v = *(const uint4*)(sp + c4 * 8);
                    const ushort_t* vp = (const ushort_t*)&v;
#pragma unroll
                    for (int k = 0; k < 8; ++k)
                        a[c4] = fmaf(h2f(vp[k]), wp[(cB * 32 + c4 * 8 + k) * 9], a[c4]);
                }
            }
        }
    }
    float acc = (a[0] + a[1]) + (a[2] + a[3]);
    out[i] = 1.f / (1.f + __expf(-acc));
}

extern "C" void kernel_launch(void* const* d_in, const int* in_sizes, int n_in,
                              void* d_out, int out_size, void* d_ws, size_t ws_size,
                              hipStream_t stream)
{
    const float* feats = (const float*)d_in[0];   // [4,256,64,64]
    const float* masks = (const float*)d_in[1];   // [4,8,64,64]
    const float* enc_w = (const float*)d_in[4];   // [128,257,3,3]
    const float* enc_b = (const float*)d_in[5];
    const float* gcn_w = (const float*)d_in[6];   // [128,256,3,3]
    const float* gcn_b = (const float*)d_in[7];
    const float* ro_w  = (const float*)d_in[8];   // [1,384,3,3]
    const float* ro_b  = (const float*)d_in[9];
    float* out = (float*)d_out;                   // [4,8,64,64]

    // workspace: fp16 region then fp32 region (16B-aligned)
    ushort_t* WencF  = (ushort_t*)d_ws;           // 294912
    ushort_t* WgcnS  = WencF + 294912;            // 147456
    ushort_t* WgcnD  = WgcnS + 147456;            // 147456
    ushort_t* featsT = WgcnD + 147456;            // [4][8cc][4096][32]
    ushort_t* Sa     = featsT + 4194304;          // [32][4cc][4096][32]
    ushort_t* Sb     = Sa + 16777216;
    ushort_t* USum   = Sb + 16777216;             // [4][4cc][4096][32]
    float*    U1p    = (float*)(USum + 2097152);  // [4 kz][4 img][4096][128] fp32
    float*    U2     = U1p + 8388608;             // [4][4096][128] fp32
    float*    YR     = U2 + 2097152;              // 4*4096 fp32

    dim3 blk(256);

    hipMemsetAsync(YR, 0, 4 * 4096 * sizeof(float), stream);
    prep_weights<<<2304, blk, 0, stream>>>(enc_w, gcn_w, WencF, WgcnS, WgcnD);
    feats_to_hwc<<<dim3(64, 4, 4), blk, 0, stream>>>(feats, featsT);

    // encoder shared conv: 4 ci-quad partials (kz), K=576 each
    conv_mfma<<<dim3(32, 4, 4), blk, 0, stream>>>(
        nullptr, nullptr, nullptr, 0, featsT, WencF, U1p, 4, 8, 2);
    enc_obj_sum<<<1024, blk, 0, stream>>>(masks, enc_w, enc_b, U1p, Sa, USum);

    // 2 message-passing steps, fused 36-image conv + combine
    conv_mfma<<<dim3(32, 36, 1), blk, 0, stream>>>(
        Sa, WgcnD, Sb, 32, USum, WgcnS, U2, 4, 4, 4);
    combine_sum<<<1024, blk, 0, stream>>>(Sb, U2, gcn_b, USum);

    conv_mfma<<<dim3(32, 36, 1), blk, 0, stream>>>(
        Sb, WgcnD, Sa, 32, USum, WgcnS, U2, 4, 4, 4);
    combine_sum<<<1024, blk, 0, stream>>>(Sa, U2, gcn_b, USum);

    // readout (final states in Sa)
    ro_shared<<<512, blk, 0, stream>>>(feats, ro_w, YR);
    ro_obj<<<512, blk, 0, stream>>>(Sa, ro_w, ro_b, YR, out);
}

// Round 8
// 274.282 us; speedup vs baseline: 2.0356x; 1.1277x over previous
//
#include <hip/hip_runtime.h>
#include <math.h>

// B=4, O=8, C=256, HID=128, H=W=64, STEPS=2
// m97-style MFMA conv (global_load_lds dbuf staging) + XOR bank swizzle:
// chunked fp16 activation tensors store the 16B unit for logical quad ql of
// px-line p at position ql ^ f(p), f(p) = ((p>>1)+(p>>3))&3 (involution).
// Packed weights swizzle by co the same way. glds copies bytes verbatim ->
// LDS image is swizzled -> fragment reads spread across bank groups.
//   enc:  relu(conv(feats,Wf) [4 ci-quad partials] + conv(mask,Wm) + b)
//   gcn:  relu(conv(s_i,W1-W2) [raw] + conv(Sum,W2) + b)  -- one 36-img dispatch
//   ro :  sigmoid(conv(feats,Wa) + conv(s,Wb) + b)        -- reg-resident weights

typedef unsigned short ushort_t;
typedef _Float16 f16x8 __attribute__((ext_vector_type(8)));
typedef float f32x4 __attribute__((ext_vector_type(4)));

#define GLDS(gsrc, ldst)                                                      \
    __builtin_amdgcn_global_load_lds(                                         \
        (const __attribute__((address_space(1))) unsigned int*)(gsrc),        \
        (__attribute__((address_space(3))) unsigned int*)(ldst), 16, 0, 0)

__device__ __forceinline__ ushort_t f2h(float f) {
    _Float16 h = (_Float16)f;
    return *(ushort_t*)&h;
}
__device__ __forceinline__ float h2f(ushort_t u) {
    _Float16 h = *(_Float16*)&u;
    return (float)h;
}
__device__ __forceinline__ int swz(int p, int q) {   // p: 0..63 line index
    return q ^ (((p >> 1) + (p >> 3)) & 3);
}

// ---- weight packing (co-swizzled): WencF[t][cc8][co128][ci32],
// WgcnS/D[t][cc4][co128][ci32]; readout: WroQ[8cc][4q][9t][8k], WroS[4cc][4q][9t][8k]
__global__ __launch_bounds__(256) void prep_weights(
    const float* __restrict__ enc_w, const float* __restrict__ gcn_w,
    const float* __restrict__ ro_w,
    ushort_t* __restrict__ WencF, ushort_t* __restrict__ WgcnS,
    ushort_t* __restrict__ WgcnD, ushort_t* __restrict__ WroQ,
    ushort_t* __restrict__ WroS)
{
    int i = blockIdx.x * 256 + threadIdx.x;
    if (i < 294912) {
        int u8 = i & 7, q = (i >> 3) & 3, co = (i >> 5) & 127, tc = i >> 12;
        int t = tc >> 3, cc = tc & 7;
        int ci = cc * 32 + swz(co & 63, q) * 8 + u8;   // logical quad = swz(co,q)
        WencF[i] = f2h(enc_w[(co * 257 + ci) * 9 + t]);
    } else if (i < 442368) {
        int j = i - 294912;
        int u8 = j & 7, q = (j >> 3) & 3, co = (j >> 5) & 127, tc = j >> 12;
        int t = tc >> 2, cc = tc & 3;
        int ci = cc * 32 + swz(co & 63, q) * 8 + u8;
        WgcnS[j] = f2h(gcn_w[(co * 256 + 128 + ci) * 9 + t]);
    } else if (i < 589824) {
        int j = i - 442368;
        int u8 = j & 7, q = (j >> 3) & 3, co = (j >> 5) & 127, tc = j >> 12;
        int t = tc >> 2, cc = tc & 3;
        int ci = cc * 32 + swz(co & 63, q) * 8 + u8;
        WgcnD[j] = f2h(gcn_w[(co * 256 + ci) * 9 + t] - gcn_w[(co * 256 + 128 + ci) * 9 + t]);
    } else if (i < 592128) {          // WroQ: 2304
        int j = i - 589824;
        int k = j & 7, r = j >> 3;
        int t = r % 9, cq = r / 9, q = cq & 3, cc = cq >> 2;
        WroQ[j] = f2h(ro_w[(cc * 32 + q * 8 + k) * 9 + t]);
    } else if (i < 593280) {          // WroS: 1152
        int j = i - 592128;
        int k = j & 7, r = j >> 3;
        int t = r % 9, cq = r / 9, q = cq & 3, cc = cq >> 2;
        WroS[j] = f2h(ro_w[(256 + cc * 32 + q * 8 + k) * 9 + t]);
    }
}

// ---- feats fp32 CHW -> fp16 chunked+swizzled HWC [4][cc8][4096][32]
__global__ __launch_bounds__(256) void feats_to_hwc(const float* __restrict__ feats,
                                                    ushort_t* __restrict__ featsT)
{
    __shared__ float tile[64][65];
    int img = blockIdx.z, ct = blockIdx.y, pt = blockIdx.x;   // pt = row
    int t = threadIdx.x;
    int px_l = t & 63;
    const float* src = feats + ((size_t)img * 256 + ct * 64) * 4096 + pt * 64;
#pragma unroll
    for (int j = 0; j < 16; ++j) {
        int ci_l = (t >> 6) + j * 4;
        tile[px_l][ci_l] = src[(size_t)ci_l * 4096 + px_l];
    }
    __syncthreads();
    int px = t >> 2;
#pragma unroll
    for (int j = 0; j < 2; ++j) {
        int c8 = ((t & 3) + j * 4) * 8;
        uint4 v; ushort_t* pv = (ushort_t*)&v;
#pragma unroll
        for (int k = 0; k < 8; ++k) pv[k] = f2h(tile[px][c8 + k]);
        int cc = ct * 2 + (c8 >> 5);
        int q = (c8 & 31) >> 3;
        *(uint4*)(featsT + ((size_t)img * 8 + cc) * 131072 +
                  (size_t)(pt * 64 + px) * 32 + swz(px, q) * 8) = v;
    }
}

// ---- main conv (m97 structure). Swizzled fragment offsets precomputed.
__global__ __launch_bounds__(256, 3) void conv_mfma(
    const ushort_t* __restrict__ xA, const ushort_t* __restrict__ WA,
    ushort_t* __restrict__ outA, int nA,
    const ushort_t* __restrict__ xB, const ushort_t* __restrict__ WB,
    float* __restrict__ outB, int nB,
    int ncc_img, int ncc_blk)
{
    __shared__ ushort_t raw[25088];           // 50176 B
    ushort_t* xs = raw;                       // 2 x [4 rows][66 cols][32ci]
    ushort_t* wlds = raw + 16896;             // 2 x [128 co][32ci]
    ushort_t* eb16 = raw;                     // epilogue overlay [64][136]
    float* eb32 = (float*)raw;                // epilogue overlay [64][68]

    const int rp = blockIdx.x, img = blockIdx.y, kz = blockIdx.z;
    const int row0 = rp * 2;
    const int cc0 = kz * ncc_blk;
    const int nchunk = 9 * ncc_blk;
    const int tid = threadIdx.x;
    const int w = tid >> 6, lane = tid & 63, lq = lane >> 4, lr = lane & 15;
    const int cg = w >> 1, pg = w & 1;

    const bool isA = img < nA;
    const ushort_t* x = isA ? xA + (size_t)img * ncc_img * 131072
                            : xB + (size_t)(img - nA) * ncc_img * 131072;
    const ushort_t* W = isA ? WA : WB;

    // swizzled fragment offsets (loop-invariant, per-lane VGPRs)
    int aoff[4], boff[3][4];
#pragma unroll
    for (int cf = 0; cf < 4; ++cf) {
        int co = cg * 64 + cf * 16 + lr;
        aoff[cf] = co * 32 + swz(co & 63, lq) * 8;
    }
#pragma unroll
    for (int dx = 0; dx < 3; ++dx)
#pragma unroll
        for (int p = 0; p < 4; ++p) {
            int col = dx + lr + p * 16;                 // LDS col 0..65; global px = col-1
            boff[dx][p] = col * 32 + swz((col - 1) & 63, lq) * 8;
        }

    // zero the halo columns (col 0 and 65) of both act buffers, once
    if (tid < 64) {
        int b = tid >> 5, r = (tid >> 3) & 3, c = (tid >> 2) & 1, s = tid & 3;
        *(uint4*)(xs + b * 8448 + r * 2112 + (c ? 65 : 0) * 32 + s * 8) =
            make_uint4(0, 0, 0, 0);
    }

    f32x4 acc[4][4];
#pragma unroll
    for (int a = 0; a < 4; ++a)
#pragma unroll
        for (int p = 0; p < 4; ++p) acc[a][p] = (f32x4){0.f, 0.f, 0.f, 0.f};

    const int gy = row0 - 1 + w;
    const bool row_ok = (unsigned)gy < 64u;
#define STAGE_ACT(cc_, buf_)                                                    \
    {                                                                           \
        ushort_t* dst = xs + (buf_) * 8448 + w * 2112 + 32;                     \
        if (row_ok) {                                                           \
            const ushort_t* src = x + (size_t)(cc_) * 131072 + (size_t)gy * 2048; \
            GLDS(src + 0 * 512 + lane * 8, dst + 0 * 512);                      \
            GLDS(src + 1 * 512 + lane * 8, dst + 1 * 512);                      \
            GLDS(src + 2 * 512 + lane * 8, dst + 2 * 512);                      \
            GLDS(src + 3 * 512 + lane * 8, dst + 3 * 512);                      \
        } else {                                                                \
            *(uint4*)(dst + 0 * 512 + lane * 8) = make_uint4(0, 0, 0, 0);       \
            *(uint4*)(dst + 1 * 512 + lane * 8) = make_uint4(0, 0, 0, 0);       \
            *(uint4*)(dst + 2 * 512 + lane * 8) = make_uint4(0, 0, 0, 0);       \
            *(uint4*)(dst + 3 * 512 + lane * 8) = make_uint4(0, 0, 0, 0);       \
        }                                                                       \
    }
#define STAGE_W(t_, cc_, buf_)                                                  \
    {                                                                           \
        const ushort_t* src = W + ((size_t)((t_) * ncc_img + (cc_)) * 4096);    \
        ushort_t* dst = wlds + (buf_) * 4096;                                   \
        GLDS(src + (w * 2 + 0) * 512 + lane * 8, dst + (w * 2 + 0) * 512);      \
        GLDS(src + (w * 2 + 1) * 512 + lane * 8, dst + (w * 2 + 1) * 512);      \
    }

    STAGE_ACT(cc0, 0);
    STAGE_W(0, cc0, 0);

    int kc = 0;
    for (int ccl = 0; ccl < ncc_blk; ++ccl) {
        const int cc = cc0 + ccl;
        const int xb = ccl & 1;
#pragma unroll
        for (int t = 0; t < 9; ++t, ++kc) {
            __syncthreads();
            if (kc + 1 < nchunk) {
                if (t == 8) {
                    STAGE_W(0, cc + 1, (kc + 1) & 1);
                    STAGE_ACT(cc + 1, (ccl + 1) & 1);
                } else {
                    STAGE_W(t + 1, cc, (kc + 1) & 1);
                }
            }
            const int dy = t / 3, dx = t - 3 * dy;
            const ushort_t* wl = wlds + (kc & 1) * 4096;
            const ushort_t* xl = xs + xb * 8448 + (pg + dy) * 2112;
            f16x8 A0 = *(const f16x8*)(wl + aoff[0]);
            f16x8 A1 = *(const f16x8*)(wl + aoff[1]);
            f16x8 A2 = *(const f16x8*)(wl + aoff[2]);
            f16x8 A3 = *(const f16x8*)(wl + aoff[3]);
#pragma unroll
            for (int p = 0; p < 4; ++p) {
                f16x8 Bf = *(const f16x8*)(xl + boff[dx][p]);
                acc[0][p] = __builtin_amdgcn_mfma_f32_16x16x32_f16(A0, Bf, acc[0][p], 0, 0, 0);
                acc[1][p] = __builtin_amdgcn_mfma_f32_16x16x32_f16(A1, Bf, acc[1][p], 0, 0, 0);
                acc[2][p] = __builtin_amdgcn_mfma_f32_16x16x32_f16(A2, Bf, acc[2][p], 0, 0, 0);
                acc[3][p] = __builtin_amdgcn_mfma_f32_16x16x32_f16(A3, Bf, acc[3][p], 0, 0, 0);
            }
        }
    }

    // ---- epilogue (raw). A: fp16 chunked+swizzled. B: fp32 [px][128].
    if (isA) {
        ushort_t* obase = outA + (size_t)img * ncc_img * 131072;
#pragma unroll
        for (int r = 0; r < 2; ++r) {
            __syncthreads();
            if (pg == r) {
#pragma unroll
                for (int cf = 0; cf < 4; ++cf)
#pragma unroll
                    for (int pf = 0; pf < 4; ++pf) {
                        int px = pf * 16 + lr;
                        int co_l = cg * 64 + cf * 16 + lq * 4;
                        ushort_t pk[4];
#pragma unroll
                        for (int j = 0; j < 4; ++j) pk[j] = f2h(acc[cf][pf][j]);
                        *(uint2*)(eb16 + px * 136 + co_l) = *(uint2*)pk;
                    }
            }
            __syncthreads();
#pragma unroll
            for (int k = 0; k < 4; ++k) {
                int i = tid + k * 256;
                int px = i >> 4, c16 = i & 15;
                uint4 v = *(uint4*)(eb16 + px * 136 + c16 * 8);
                *(uint4*)(obase + (size_t)(c16 >> 2) * 131072 +
                          (size_t)((row0 + r) * 64 + px) * 32 + swz(px, c16 & 3) * 8) = v;
            }
        }
    } else {
        float* obase = outB + ((size_t)kz * nB + (img - nA)) * 524288;
#pragma unroll
        for (int r = 0; r < 2; ++r)
#pragma unroll
            for (int h = 0; h < 2; ++h) {
                __syncthreads();
                if (pg == r && cg == h) {
#pragma unroll
                    for (int cf = 0; cf < 4; ++cf)
#pragma unroll
                        for (int pf = 0; pf < 4; ++pf)
                            *(f32x4*)(eb32 + (pf * 16 + lr) * 68 + cf * 16 + lq * 4) =
                                acc[cf][pf];
                }
                __syncthreads();
                for (int i = tid; i < 512; i += 256) {
                    int px = i >> 3, cl = (i & 7) * 8;
                    f32x4 v0 = *(f32x4*)(eb32 + px * 68 + cl);
                    f32x4 v1 = *(f32x4*)(eb32 + px * 68 + cl + 4);
                    float* op = obase + (size_t)((row0 + r) * 64 + px) * 128 + h * 64 + cl;
                    *(f32x4*)op = v0;
                    *(f32x4*)(op + 4) = v1;
                }
            }
    }
#undef STAGE_ACT
#undef STAGE_W
}

// ---- gcn combine: S = relu(S_raw + U2[b] + gcn_b), USum = sum_o S (swizzled io)
__global__ __launch_bounds__(256) void combine_sum(
    ushort_t* __restrict__ S, const float* __restrict__ U2,
    const float* __restrict__ gcn_b, ushort_t* __restrict__ USum)
{
    int i = blockIdx.x * 256 + threadIdx.x;   // b(2)|px(12)|c16(4)
    int c8 = i & 15, px = (i >> 4) & 4095, b = i >> 16;
    int co = c8 * 8;
    size_t coff = (size_t)(c8 >> 2) * 131072 + (size_t)px * 32 + swz(px & 63, c8 & 3) * 8;
    const float* u = U2 + ((size_t)b * 4096 + px) * 128 + co;
    float base[8];
#pragma unroll
    for (int k = 0; k < 8; ++k) base[k] = u[k] + gcn_b[co + k];
    float s[8] = {0, 0, 0, 0, 0, 0, 0, 0};
#pragma unroll
    for (int o = 0; o < 8; ++o) {
        ushort_t* p = S + (size_t)(b * 8 + o) * 524288 + coff;
        uint4 v = *(uint4*)p;
        ushort_t* vp = (ushort_t*)&v;
        uint4 sv; ushort_t* sp = (ushort_t*)&sv;
#pragma unroll
        for (int k = 0; k < 8; ++k) {
            float f = fmaxf(h2f(vp[k]) + base[k], 0.f);
            s[k] += f;
            sp[k] = f2h(f);
        }
        *(uint4*)p = sv;
    }
    uint4 sv; ushort_t* sp = (ushort_t*)&sv;
#pragma unroll
    for (int k = 0; k < 8; ++k) sp[k] = f2h(s[k]);
    *(uint4*)(USum + (size_t)b * 524288 + coff) = sv;
}

// ---- encoder per-object part + object-sum (4 fp32 partials in, swizzled out)
__global__ __launch_bounds__(256) void enc_obj_sum(
    const float* __restrict__ masks, const float* __restrict__ enc_w,
    const float* __restrict__ enc_b, const float* __restrict__ U1p,
    ushort_t* __restrict__ S, ushort_t* __restrict__ USum)
{
    int i = blockIdx.x * 256 + threadIdx.x;   // b(2)|px(12)|c16(4)
    int c8 = i & 15, px = (i >> 4) & 4095, b = i >> 16;
    int co = c8 * 8;
    int y = px >> 6, xx = px & 63;
    size_t coff = (size_t)(c8 >> 2) * 131072 + (size_t)px * 32 + swz(px & 63, c8 & 3) * 8;
    const float* p0 = U1p + ((size_t)b * 4096 + px) * 128 + co;
    float base[8];
#pragma unroll
    for (int k = 0; k < 8; ++k)
        base[k] = ((p0[k] + p0[k + 2097152]) + (p0[k + 4194304] + p0[k + 6291456]))
                  + enc_b[co + k];
    float wm[8][9];
#pragma unroll
    for (int k = 0; k < 8; ++k) {
        const float* wp = enc_w + (size_t)((co + k) * 257 + 256) * 9;
#pragma unroll
        for (int t = 0; t < 9; ++t) wm[k][t] = wp[t];
    }
    float s[8] = {0, 0, 0, 0, 0, 0, 0, 0};
#pragma unroll
    for (int o = 0; o < 8; ++o) {
        const float* m = masks + (size_t)(b * 8 + o) * 4096;
        float mt[9];
#pragma unroll
        for (int dy = 0; dy < 3; ++dy)
#pragma unroll
            for (int dx = 0; dx < 3; ++dx) {
                int gy_ = y + dy - 1, gx = xx + dx - 1;
                mt[dy * 3 + dx] =
                    ((unsigned)gy_ < 64u && (unsigned)gx < 64u) ? m[gy_ * 64 + gx] : 0.f;
            }
        uint4 sv; ushort_t* sp = (ushort_t*)&sv;
#pragma unroll
        for (int k = 0; k < 8; ++k) {
            float acc = base[k];
#pragma unroll
            for (int t = 0; t < 9; ++t) acc = fmaf(mt[t], wm[k][t], acc);
            acc = fmaxf(acc, 0.f);
            s[k] += acc;
            sp[k] = f2h(acc);
        }
        *(uint4*)(S + (size_t)(b * 8 + o) * 524288 + coff) = sv;
    }
    uint4 sv; ushort_t* sp = (ushort_t*)&sv;
#pragma unroll
    for (int k = 0; k < 8; ++k) sp[k] = f2h(s[k]);
    *(uint4*)(USum + (size_t)b * 524288 + coff) = sv;
}

// ---- readout shared part: thread = 8 ci x 9 taps, weights in regs
__global__ __launch_bounds__(256) void ro_shared(
    const ushort_t* __restrict__ featsT, const ushort_t* __restrict__ WroQ,
    float* __restrict__ YR)
{
    int i = blockIdx.x * 256 + threadIdx.x;   // b(2)|px(12)|cu(5)
    int cu = i & 31, px = (i >> 5) & 4095, b = i >> 17;
    int cc = cu >> 2, q = cu & 3;
    int y = px >> 6, xcol = px & 63;
    const ushort_t* wp = WroQ + (size_t)(cc * 4 + q) * 72;
    float wreg[9][8];
#pragma unroll
    for (int t = 0; t < 9; ++t) {
        uint4 wv = *(const uint4*)(wp + t * 8);
        const ushort_t* wq = (const ushort_t*)&wv;
#pragma unroll
        for (int k = 0; k < 8; ++k) wreg[t][k] = h2f(wq[k]);
    }
    const ushort_t* fb = featsT + (size_t)(b * 8 + cc) * 131072;
    float acc = 0.f;
#pragma unroll
    for (int dy = 0; dy < 3; ++dy) {
        int gy = y + dy - 1;
        if ((unsigned)gy >= 64u) continue;
#pragma unroll
        for (int dx = 0; dx < 3; ++dx) {
            int gx = xcol + dx - 1;
            if ((unsigned)gx >= 64u) continue;
            uint4 v = *(const uint4*)(fb + (size_t)(gy * 64 + gx) * 32 + swz(gx, q) * 8);
            const ushort_t* vp = (const ushort_t*)&v;
#pragma unroll
            for (int k = 0; k < 8; ++k)
                acc = fmaf(h2f(vp[k]), wreg[dy * 3 + dx][k], acc);
        }
    }
#pragma unroll
    for (int d = 16; d >= 1; d >>= 1) acc += __shfl_down(acc, d, 32);
    if (cu == 0) YR[b * 4096 + px] = acc;
}

// ---- readout per-object part: thread = 8 ci x 9 taps + sigmoid
__global__ __launch_bounds__(256) void ro_obj(
    const ushort_t* __restrict__ S, const ushort_t* __restrict__ WroS,
    const float* __restrict__ ro_b, const float* __restrict__ YR,
    float* __restrict__ out)
{
    int i = blockIdx.x * 256 + threadIdx.x;   // n(5)|px(12)|cu(4)
    int cu = i & 15, px = (i >> 4) & 4095, n = i >> 16;
    int b = n >> 3;
    int cc = cu >> 2, q = cu & 3;
    int y = px >> 6, xcol = px & 63;
    const ushort_t* wp = WroS + (size_t)(cc * 4 + q) * 72;
    float wreg[9][8];
#pragma unroll
    for (int t = 0; t < 9; ++t) {
        uint4 wv = *(const uint4*)(wp + t * 8);
        const ushort_t* wq = (const ushort_t*)&wv;
#pragma unroll
        for (int k = 0; k < 8; ++k) wreg[t][k] = h2f(wq[k]);
    }
    const ushort_t* sb = S + ((size_t)n * 4 + cc) * 131072;
    float acc = 0.f;
#pragma unroll
    for (int dy = 0; dy < 3; ++dy) {
        int gy = y + dy - 1;
        if ((unsigned)gy >= 64u) continue;
#pragma unroll
        for (int dx = 0; dx < 3; ++dx) {
            int gx = xcol + dx - 1;
            if ((unsigned)gx >= 64u) continue;
            uint4 v = *(const uint4*)(sb + (size_t)(gy * 64 + gx) * 32 + swz(gx, q) * 8);
            const ushort_t* vp = (const ushort_t*)&v;
#pragma unroll
            for (int k = 0; k < 8; ++k)
                acc = fmaf(h2f(vp[k]), wreg[dy * 3 + dx][k], acc);
        }
    }
#pragma unroll
    for (int d = 8; d >= 1; d >>= 1) acc += __shfl_down(acc, d, 16);
    if (cu == 0) {
        float v = acc + YR[b * 4096 + px] + ro_b[0];
        out[n * 4096 + px] = 1.f / (1.f + __expf(-v));
    }
}

extern "C" void kernel_launch(void* const* d_in, const int* in_sizes, int n_in,
                              void* d_out, int out_size, void* d_ws, size_t ws_size,
                              hipStream_t stream)
{
    const float* feats = (const float*)d_in[0];   // [4,256,64,64]
    const float* masks = (const float*)d_in[1];   // [4,8,64,64]
    const float* enc_w = (const float*)d_in[4];   // [128,257,3,3]
    const float* enc_b = (const float*)d_in[5];
    const float* gcn_w = (const float*)d_in[6];   // [128,256,3,3]
    const float* gcn_b = (const float*)d_in[7];
    const float* ro_w  = (const float*)d_in[8];   // [1,384,3,3]
    const float* ro_b  = (const float*)d_in[9];
    float* out = (float*)d_out;                   // [4,8,64,64]

    // workspace: fp16 region then fp32 region (16B-aligned)
    ushort_t* WencF  = (ushort_t*)d_ws;           // 294912
    ushort_t* WgcnS  = WencF + 294912;            // 147456
    ushort_t* WgcnD  = WgcnS + 147456;            // 147456
    ushort_t* WroQ   = WgcnD + 147456;            // 2304
    ushort_t* WroS   = WroQ + 2304;               // 1152
    ushort_t* featsT = WroS + 1152;               // [4][8cc][4096][32]
    ushort_t* Sa     = featsT + 4194304;          // [32][4cc][4096][32]
    ushort_t* Sb     = Sa + 16777216;
    ushort_t* USum   = Sb + 16777216;             // [4][4cc][4096][32]
    float*    U1p    = (float*)(USum + 2097152);  // [4 kz][4 img][4096][128] fp32
    float*    U2     = U1p + 8388608;             // [4][4096][128] fp32
    float*    YR     = U2 + 2097152;              // 4*4096 fp32

    dim3 blk(256);

    prep_weights<<<2320, blk, 0, stream>>>(enc_w, gcn_w, ro_w,
                                           WencF, WgcnS, WgcnD, WroQ, WroS);
    feats_to_hwc<<<dim3(64, 4, 4), blk, 0, stream>>>(feats, featsT);

    // encoder shared conv: 4 ci-quad partials (kz), K=576 each
    conv_mfma<<<dim3(32, 4, 4), blk, 0, stream>>>(
        nullptr, nullptr, nullptr, 0, featsT, WencF, U1p, 4, 8, 2);
    enc_obj_sum<<<1024, blk, 0, stream>>>(masks, enc_w, enc_b, U1p, Sa, USum);

    // 2 message-passing steps, fused 36-image conv + combine
    conv_mfma<<<dim3(32, 36, 1), blk, 0, stream>>>(
        Sa, WgcnD, Sb, 32, USum, WgcnS, U2, 4, 4, 4);
    combine_sum<<<1024, blk, 0, stream>>>(Sb, U2, gcn_b, USum);

    conv_mfma<<<dim3(32, 36, 1), blk, 0, stream>>>(
        Sb, WgcnD, Sa, 32, USum, WgcnS, U2, 4, 4, 4);
    combine_sum<<<1024, blk, 0, stream>>>(Sa, U2, gcn_b, USum);

    // readout (final states in Sa)
    ro_shared<<<2048, blk, 0, stream>>>(featsT, WroQ, YR);
    ro_obj<<<8192, blk, 0, stream>>>(Sa, WroS, ro_b, YR, out);
}

// Round 9
// 272.814 us; speedup vs baseline: 2.0466x; 1.0054x over previous
//
#include <hip/hip_runtime.h>
#include <math.h>

// B=4, O=8, C=256, HID=128, H=W=64, STEPS=2
// MFMA conv, m97-style glds staging, 3-tap weight groups (deep prefetch):
// per ci-chunk (K=32): acts staged once (single buffer, dedicated phase);
// weights staged per dy-group (3 taps, 24KB) into a 2-deep ring, prefetched
// one full compute phase (~230cyc) ahead so the barrier's vmcnt(0) drain hits
// already-landed loads. 4 barriers per ci-chunk vs 9 before.
//   enc:  relu(conv(feats,Wf) [4 ci-quad partials] + conv(mask,Wm) + b)
//   gcn:  relu(conv(s_i,W1-W2) [raw] + conv(Sum,W2) + b)  -- one 36-img dispatch
//   ro :  sigmoid(conv(feats,Wa) + conv(s,Wb) + b)        -- reg-resident weights

typedef unsigned short ushort_t;
typedef _Float16 f16x8 __attribute__((ext_vector_type(8)));
typedef float f32x4 __attribute__((ext_vector_type(4)));

#define GLDS(gsrc, ldst)                                                      \
    __builtin_amdgcn_global_load_lds(                                         \
        (const __attribute__((address_space(1))) unsigned int*)(gsrc),        \
        (__attribute__((address_space(3))) unsigned int*)(ldst), 16, 0, 0)

__device__ __forceinline__ ushort_t f2h(float f) {
    _Float16 h = (_Float16)f;
    return *(ushort_t*)&h;
}
__device__ __forceinline__ float h2f(ushort_t u) {
    _Float16 h = *(_Float16*)&u;
    return (float)h;
}

// ---- weight packing: WencF[t][cc8][co128][ci32], WgcnS/D[t][cc4][co128][ci32]
// readout: WroQ[8cc][4q][9t][8k], WroS[4cc][4q][9t][8k]
__global__ __launch_bounds__(256) void prep_weights(
    const float* __restrict__ enc_w, const float* __restrict__ gcn_w,
    const float* __restrict__ ro_w,
    ushort_t* __restrict__ WencF, ushort_t* __restrict__ WgcnS,
    ushort_t* __restrict__ WgcnD, ushort_t* __restrict__ WroQ,
    ushort_t* __restrict__ WroS)
{
    int i = blockIdx.x * 256 + threadIdx.x;
    if (i < 294912) {
        int ci32 = i & 31, co = (i >> 5) & 127, tc = i >> 12;   // tc = t*8+cc
        int t = tc >> 3, cc = tc & 7, ci = cc * 32 + ci32;
        WencF[i] = f2h(enc_w[(co * 257 + ci) * 9 + t]);
    } else if (i < 442368) {
        int j = i - 294912;
        int ci32 = j & 31, co = (j >> 5) & 127, tc = j >> 12;   // t*4+cc
        int t = tc >> 2, cc = tc & 3, ci = cc * 32 + ci32;
        WgcnS[j] = f2h(gcn_w[(co * 256 + 128 + ci) * 9 + t]);
    } else if (i < 589824) {
        int j = i - 442368;
        int ci32 = j & 31, co = (j >> 5) & 127, tc = j >> 12;
        int t = tc >> 2, cc = tc & 3, ci = cc * 32 + ci32;
        WgcnD[j] = f2h(gcn_w[(co * 256 + ci) * 9 + t] - gcn_w[(co * 256 + 128 + ci) * 9 + t]);
    } else if (i < 592128) {          // WroQ: 2304
        int j = i - 589824;
        int k = j & 7, r = j >> 3;
        int t = r % 9, cq = r / 9, q = cq & 3, cc = cq >> 2;
        WroQ[j] = f2h(ro_w[(cc * 32 + q * 8 + k) * 9 + t]);
    } else if (i < 593280) {          // WroS: 1152
        int j = i - 592128;
        int k = j & 7, r = j >> 3;
        int t = r % 9, cq = r / 9, q = cq & 3, cc = cq >> 2;
        WroS[j] = f2h(ro_w[(256 + cc * 32 + q * 8 + k) * 9 + t]);
    }
}

// ---- feats fp32 CHW -> fp16 chunked HWC [4][cc8][4096][32]
__global__ __launch_bounds__(256) void feats_to_hwc(const float* __restrict__ feats,
                                                    ushort_t* __restrict__ featsT)
{
    __shared__ float tile[64][65];
    int img = blockIdx.z, ct = blockIdx.y, pt = blockIdx.x;   // pt = row
    int t = threadIdx.x;
    int px_l = t & 63;
    const float* src = feats + ((size_t)img * 256 + ct * 64) * 4096 + pt * 64;
#pragma unroll
    for (int j = 0; j < 16; ++j) {
        int ci_l = (t >> 6) + j * 4;
        tile[px_l][ci_l] = src[(size_t)ci_l * 4096 + px_l];
    }
    __syncthreads();
    int px = t >> 2;
#pragma unroll
    for (int j = 0; j < 2; ++j) {
        int c8 = ((t & 3) + j * 4) * 8;
        uint4 v; ushort_t* pv = (ushort_t*)&v;
#pragma unroll
        for (int k = 0; k < 8; ++k) pv[k] = f2h(tile[px][c8 + k]);
        int cc = ct * 2 + (c8 >> 5);
        *(uint4*)(featsT + ((size_t)img * 8 + cc) * 131072 +
                  (size_t)(pt * 64 + px) * 32 + (c8 & 31)) = v;
    }
}

// ---- main conv. grid (32 rowpairs, nA+nB imgs, kz). block 256, 4 waves (cg,pg).
// Block tile: 128 co x 128 px (2 rows); wave: 64 co x 64 px (one row).
__global__ __launch_bounds__(256, 2) void conv_mfma(
    const ushort_t* __restrict__ xA, const ushort_t* __restrict__ WA,
    ushort_t* __restrict__ outA, int nA,
    const ushort_t* __restrict__ xB, const ushort_t* __restrict__ WB,
    float* __restrict__ outB, int nB,
    int ncc_img, int ncc_blk)
{
    __shared__ ushort_t raw[33024];           // 66048 B
    ushort_t* xs = raw;                       // [4 rows][66 cols][32ci] = 8448
    ushort_t* wlds = raw + 8448;              // 2 x [3 taps][128co][32ci] = 2 x 12288
    ushort_t* eb16 = raw;                     // epilogue overlay [64][136]
    float* eb32 = (float*)raw;                // epilogue overlay [64][68]

    const int rp = blockIdx.x, img = blockIdx.y, kz = blockIdx.z;
    const int row0 = rp * 2;
    const int cc0 = kz * ncc_blk;
    const int tid = threadIdx.x;
    const int w = tid >> 6, lane = tid & 63, lq = lane >> 4, lr = lane & 15;
    const int cg = w >> 1, pg = w & 1;

    const bool isA = img < nA;
    const ushort_t* x = isA ? xA + (size_t)img * ncc_img * 131072
                            : xB + (size_t)(img - nA) * ncc_img * 131072;
    const ushort_t* W = isA ? WA : WB;

    const int aoff0 = (cg * 64 + lr) * 32 + lq * 8;

    // zero halo columns (0 and 65) of the act buffer, once (stays zero)
    if (tid < 32) {
        int r = tid >> 3, c = (tid >> 2) & 1, s = tid & 3;
        *(uint4*)(xs + r * 2112 + (c ? 65 : 0) * 32 + s * 8) = make_uint4(0, 0, 0, 0);
    }

    f32x4 acc[4][4];
#pragma unroll
    for (int a = 0; a < 4; ++a)
#pragma unroll
        for (int p = 0; p < 4; ++p) acc[a][p] = (f32x4){0.f, 0.f, 0.f, 0.f};

    const int gy = row0 - 1 + w;
    const bool row_ok = (unsigned)gy < 64u;

    // acts: wave w stages row w (64 cols x 32 ci = 4 KB) via 4 glds
#define STAGE_ACT(cc_)                                                          \
    {                                                                           \
        ushort_t* adst = xs + w * 2112 + 32;                                    \
        if (row_ok) {                                                           \
            const ushort_t* asrc =                                              \
                x + (size_t)(cc_) * 131072 + (size_t)gy * 2048 + lane * 8;      \
            GLDS(asrc + 0 * 512, adst + 0 * 512);                               \
            GLDS(asrc + 1 * 512, adst + 1 * 512);                               \
            GLDS(asrc + 2 * 512, adst + 2 * 512);                               \
            GLDS(asrc + 3 * 512, adst + 3 * 512);                               \
        } else {                                                                \
            *(uint4*)(adst + 0 * 512 + lane * 8) = make_uint4(0, 0, 0, 0);      \
            *(uint4*)(adst + 1 * 512 + lane * 8) = make_uint4(0, 0, 0, 0);      \
            *(uint4*)(adst + 2 * 512 + lane * 8) = make_uint4(0, 0, 0, 0);      \
            *(uint4*)(adst + 3 * 512 + lane * 8) = make_uint4(0, 0, 0, 0);      \
        }                                                                       \
    }
    // weights: 3 taps (t0..t0+2) = 24 runs of 1KB; wave w takes runs w*6..w*6+5
#define STAGE_W(t0_, cc_, buf_)                                                 \
    {                                                                           \
        ushort_t* wdst = wlds + (buf_) * 12288;                                 \
        _Pragma("unroll")                                                       \
        for (int r_ = w * 6; r_ < w * 6 + 6; ++r_) {                            \
            int g_ = r_ >> 3, rem_ = (r_ & 7) * 512;                            \
            GLDS(W + ((size_t)((t0_) + g_) * ncc_img + (cc_)) * 4096 + rem_ +   \
                     lane * 8,                                                  \
                 wdst + g_ * 4096 + rem_);                                      \
        }                                                                       \
    }

    STAGE_ACT(cc0);
    STAGE_W(0, cc0, 0);

    for (int ccl = 0; ccl < ncc_blk; ++ccl) {
        const int cc = cc0 + ccl;
#pragma unroll
        for (int g = 0; g < 3; ++g) {
            __syncthreads();                  // drains glds issued last phase
            const int par = (ccl + g) & 1;
            if (g < 2) {
                STAGE_W(3 * (g + 1), cc, par ^ 1);
            } else if (ccl + 1 < ncc_blk) {
                STAGE_W(0, cc + 1, par ^ 1);
            }
            const ushort_t* wb = wlds + par * 12288;
            const ushort_t* xrow = xs + (pg + g) * 2112 + lq * 8;
#pragma unroll
            for (int dx = 0; dx < 3; ++dx) {
                const ushort_t* wt = wb + dx * 4096 + aoff0;
                f16x8 A0 = *(const f16x8*)(wt);
                f16x8 A1 = *(const f16x8*)(wt + 512);    // +16 co
                f16x8 A2 = *(const f16x8*)(wt + 1024);
                f16x8 A3 = *(const f16x8*)(wt + 1536);
#pragma unroll
                for (int p = 0; p < 4; ++p) {
                    f16x8 Bf = *(const f16x8*)(xrow + (dx + lr + p * 16) * 32);
                    acc[0][p] = __builtin_amdgcn_mfma_f32_16x16x32_f16(A0, Bf, acc[0][p], 0, 0, 0);
                    acc[1][p] = __builtin_amdgcn_mfma_f32_16x16x32_f16(A1, Bf, acc[1][p], 0, 0, 0);
                    acc[2][p] = __builtin_amdgcn_mfma_f32_16x16x32_f16(A2, Bf, acc[2][p], 0, 0, 0);
                    acc[3][p] = __builtin_amdgcn_mfma_f32_16x16x32_f16(A3, Bf, acc[3][p], 0, 0, 0);
                }
            }
        }
        if (ccl + 1 < ncc_blk) {
            __syncthreads();                  // act reads of cc done
            STAGE_ACT(cc + 1);                // short dedicated stage phase
        }
    }

    // ---- epilogue (raw). A: fp16 chunked. B: fp32 [px][128].
    if (isA) {
        ushort_t* obase = outA + (size_t)img * ncc_img * 131072;
#pragma unroll
        for (int r = 0; r < 2; ++r) {
            __syncthreads();
            if (pg == r) {
#pragma unroll
                for (int cf = 0; cf < 4; ++cf)
#pragma unroll
                    for (int pf = 0; pf < 4; ++pf) {
                        int px = pf * 16 + lr;
                        int co_l = cg * 64 + cf * 16 + lq * 4;
                        ushort_t pk[4];
#pragma unroll
                        for (int j = 0; j < 4; ++j) pk[j] = f2h(acc[cf][pf][j]);
                        *(uint2*)(eb16 + px * 136 + co_l) = *(uint2*)pk;
                    }
            }
            __syncthreads();
#pragma unroll
            for (int k = 0; k < 4; ++k) {
                int i = tid + k * 256;
                int px = i >> 4, c16 = i & 15;
                uint4 v = *(uint4*)(eb16 + px * 136 + c16 * 8);
                *(uint4*)(obase + (size_t)(c16 >> 2) * 131072 +
                          (size_t)((row0 + r) * 64 + px) * 32 + (c16 & 3) * 8) = v;
            }
        }
    } else {
        float* obase = outB + ((size_t)kz * nB + (img - nA)) * 524288;
#pragma unroll
        for (int r = 0; r < 2; ++r)
#pragma unroll
            for (int h = 0; h < 2; ++h) {
                __syncthreads();
                if (pg == r && cg == h) {
#pragma unroll
                    for (int cf = 0; cf < 4; ++cf)
#pragma unroll
                        for (int pf = 0; pf < 4; ++pf)
                            *(f32x4*)(eb32 + (pf * 16 + lr) * 68 + cf * 16 + lq * 4) =
                                acc[cf][pf];
                }
                __syncthreads();
                for (int i = tid; i < 512; i += 256) {
                    int px = i >> 3, cl = (i & 7) * 8;
                    f32x4 v0 = *(f32x4*)(eb32 + px * 68 + cl);
                    f32x4 v1 = *(f32x4*)(eb32 + px * 68 + cl + 4);
                    float* op = obase + (size_t)((row0 + r) * 64 + px) * 128 + h * 64 + cl;
                    *(f32x4*)op = v0;
                    *(f32x4*)(op + 4) = v1;
                }
            }
    }
#undef STAGE_ACT
#undef STAGE_W
}

// ---- gcn combine: S = relu(S_raw + U2[b] + gcn_b), USum = sum_o S (chunked io)
__global__ __launch_bounds__(256) void combine_sum(
    ushort_t* __restrict__ S, const float* __restrict__ U2,
    const float* __restrict__ gcn_b, ushort_t* __restrict__ USum)
{
    int i = blockIdx.x * 256 + threadIdx.x;   // b(2)|px(12)|c16(4)
    int c8 = i & 15, px = (i >> 4) & 4095, b = i >> 16;
    int co = c8 * 8;
    size_t coff = (size_t)(c8 >> 2) * 131072 + (size_t)px * 32 + (c8 & 3) * 8;
    const float* u = U2 + ((size_t)b * 4096 + px) * 128 + co;
    float base[8];
#pragma unroll
    for (int k = 0; k < 8; ++k) base[k] = u[k] + gcn_b[co + k];
    float s[8] = {0, 0, 0, 0, 0, 0, 0, 0};
#pragma unroll
    for (int o = 0; o < 8; ++o) {
        ushort_t* p = S + (size_t)(b * 8 + o) * 524288 + coff;
        uint4 v = *(uint4*)p;
        ushort_t* vp = (ushort_t*)&v;
        uint4 sv; ushort_t* sp = (ushort_t*)&sv;
#pragma unroll
        for (int k = 0; k < 8; ++k) {
            float f = fmaxf(h2f(vp[k]) + base[k], 0.f);
            s[k] += f;
            sp[k] = f2h(f);
        }
        *(uint4*)p = sv;
    }
    uint4 sv; ushort_t* sp = (ushort_t*)&sv;
#pragma unroll
    for (int k = 0; k < 8; ++k) sp[k] = f2h(s[k]);
    *(uint4*)(USum + (size_t)b * 524288 + coff) = sv;
}

// ---- encoder per-object part + object-sum (4 fp32 partials in, chunked out)
__global__ __launch_bounds__(256) void enc_obj_sum(
    const float* __restrict__ masks, const float* __restrict__ enc_w,
    const float* __restrict__ enc_b, const float* __restrict__ U1p,
    ushort_t* __restrict__ S, ushort_t* __restrict__ USum)
{
    int i = blockIdx.x * 256 + threadIdx.x;   // b(2)|px(12)|c16(4)
    int c8 = i & 15, px = (i >> 4) & 4095, b = i >> 16;
    int co = c8 * 8;
    int y = px >> 6, xx = px & 63;
    size_t coff = (size_t)(c8 >> 2) * 131072 + (size_t)px * 32 + (c8 & 3) * 8;
    const float* p0 = U1p + ((size_t)b * 4096 + px) * 128 + co;
    float base[8];
#pragma unroll
    for (int k = 0; k < 8; ++k)
        base[k] = ((p0[k] + p0[k + 2097152]) + (p0[k + 4194304] + p0[k + 6291456]))
                  + enc_b[co + k];
    float wm[8][9];
#pragma unroll
    for (int k = 0; k < 8; ++k) {
        const float* wp = enc_w + (size_t)((co + k) * 257 + 256) * 9;
#pragma unroll
        for (int t = 0; t < 9; ++t) wm[k][t] = wp[t];
    }
    float s[8] = {0, 0, 0, 0, 0, 0, 0, 0};
#pragma unroll
    for (int o = 0; o < 8; ++o) {
        const float* m = masks + (size_t)(b * 8 + o) * 4096;
        float mt[9];
#pragma unroll
        for (int dy = 0; dy < 3; ++dy)
#pragma unroll
            for (int dx = 0; dx < 3; ++dx) {
                int gy_ = y + dy - 1, gx = xx + dx - 1;
                mt[dy * 3 + dx] =
                    ((unsigned)gy_ < 64u && (unsigned)gx < 64u) ? m[gy_ * 64 + gx] : 0.f;
            }
        uint4 sv; ushort_t* sp = (ushort_t*)&sv;
#pragma unroll
        for (int k = 0; k < 8; ++k) {
            float acc = base[k];
#pragma unroll
            for (int t = 0; t < 9; ++t) acc = fmaf(mt[t], wm[k][t], acc);
            acc = fmaxf(acc, 0.f);
            s[k] += acc;
            sp[k] = f2h(acc);
        }
        *(uint4*)(S + (size_t)(b * 8 + o) * 524288 + coff) = sv;
    }
    uint4 sv; ushort_t* sp = (ushort_t*)&sv;
#pragma unroll
    for (int k = 0; k < 8; ++k) sp[k] = f2h(s[k]);
    *(uint4*)(USum + (size_t)b * 524288 + coff) = sv;
}

// ---- readout shared part: thread = 8 ci x 9 taps, weights in regs
__global__ __launch_bounds__(256) void ro_shared(
    const ushort_t* __restrict__ featsT, const ushort_t* __restrict__ WroQ,
    float* __restrict__ YR)
{
    int i = blockIdx.x * 256 + threadIdx.x;   // b(2)|px(12)|cu(5)
    int cu = i & 31, px = (i >> 5) & 4095, b = i >> 17;
    int cc = cu >> 2, q = cu & 3;
    int y = px >> 6, xcol = px & 63;
    const ushort_t* wp = WroQ + (size_t)(cc * 4 + q) * 72;
    float wreg[9][8];
#pragma unroll
    for (int t = 0; t < 9; ++t) {
        uint4 wv = *(const uint4*)(wp + t * 8);
        const ushort_t* wq = (const ushort_t*)&wv;
#pragma unroll
        for (int k = 0; k < 8; ++k) wreg[t][k] = h2f(wq[k]);
    }
    const ushort_t* fb = featsT + (size_t)(b * 8 + cc) * 131072 + q * 8;
    float acc = 0.f;
#pragma unroll
    for (int dy = 0; dy < 3; ++dy) {
        int gy = y + dy - 1;
        if ((unsigned)gy >= 64u) continue;
#pragma unroll
        for (int dx = 0; dx < 3; ++dx) {
            int gx = xcol + dx - 1;
            if ((unsigned)gx >= 64u) continue;
            uint4 v = *(const uint4*)(fb + (size_t)(gy * 64 + gx) * 32);
            const ushort_t* vp = (const ushort_t*)&v;
#pragma unroll
            for (int k = 0; k < 8; ++k)
                acc = fmaf(h2f(vp[k]), wreg[dy * 3 + dx][k], acc);
        }
    }
#pragma unroll
    for (int d = 16; d >= 1; d >>= 1) acc += __shfl_down(acc, d, 32);
    if (cu == 0) YR[b * 4096 + px] = acc;
}

// ---- readout per-object part: thread = 8 ci x 9 taps + sigmoid
__global__ __launch_bounds__(256) void ro_obj(
    const ushort_t* __restrict__ S, const ushort_t* __restrict__ WroS,
    const float* __restrict__ ro_b, const float* __restrict__ YR,
    float* __restrict__ out)
{
    int i = blockIdx.x * 256 + threadIdx.x;   // n(5)|px(12)|cu(4)
    int cu = i & 15, px = (i >> 4) & 4095, n = i >> 16;
    int b = n >> 3;
    int cc = cu >> 2, q = cu & 3;
    int y = px >> 6, xcol = px & 63;
    const ushort_t* wp = WroS + (size_t)(cc * 4 + q) * 72;
    float wreg[9][8];
#pragma unroll
    for (int t = 0; t < 9; ++t) {
        uint4 wv = *(const uint4*)(wp + t * 8);
        const ushort_t* wq = (const ushort_t*)&wv;
#pragma unroll
        for (int k = 0; k < 8; ++k) wreg[t][k] = h2f(wq[k]);
    }
    const ushort_t* sb = S + ((size_t)n * 4 + cc) * 131072 + q * 8;
    float acc = 0.f;
#pragma unroll
    for (int dy = 0; dy < 3; ++dy) {
        int gy = y + dy - 1;
        if ((unsigned)gy >= 64u) continue;
#pragma unroll
        for (int dx = 0; dx < 3; ++dx) {
            int gx = xcol + dx - 1;
            if ((unsigned)gx >= 64u) continue;
            uint4 v = *(const uint4*)(sb + (size_t)(gy * 64 + gx) * 32);
            const ushort_t* vp = (const ushort_t*)&v;
#pragma unroll
            for (int k = 0; k < 8; ++k)
                acc = fmaf(h2f(vp[k]), wreg[dy * 3 + dx][k], acc);
        }
    }
#pragma unroll
    for (int d = 8; d >= 1; d >>= 1) acc += __shfl_down(acc, d, 16);
    if (cu == 0) {
        float v = acc + YR[b * 4096 + px] + ro_b[0];
        out[n * 4096 + px] = 1.f / (1.f + __expf(-v));
    }
}

extern "C" void kernel_launch(void* const* d_in, const int* in_sizes, int n_in,
                              void* d_out, int out_size, void* d_ws, size_t ws_size,
                              hipStream_t stream)
{
    const float* feats = (const float*)d_in[0];   // [4,256,64,64]
    const float* masks = (const float*)d_in[1];   // [4,8,64,64]
    const float* enc_w = (const float*)d_in[4];   // [128,257,3,3]
    const float* enc_b = (const float*)d_in[5];
    const float* gcn_w = (const float*)d_in[6];   // [128,256,3,3]
    const float* gcn_b = (const float*)d_in[7];
    const float* ro_w  = (const float*)d_in[8];   // [1,384,3,3]
    const float* ro_b  = (const float*)d_in[9];
    float* out = (float*)d_out;                   // [4,8,64,64]

    // workspace: fp16 region then fp32 region (16B-aligned)
    ushort_t* WencF  = (ushort_t*)d_ws;           // 294912
    ushort_t* WgcnS  = WencF + 294912;            // 147456
    ushort_t* WgcnD  = WgcnS + 147456;            // 147456
    ushort_t* WroQ   = WgcnD + 147456;            // 2304
    ushort_t* WroS   = WroQ + 2304;               // 1152
    ushort_t* featsT = WroS + 1152;               // [4][8cc][4096][32]
    ushort_t* Sa     = featsT + 4194304;          // [32][4cc][4096][32]
    ushort_t* Sb     = Sa + 16777216;
    ushort_t* USum   = Sb + 16777216;             // [4][4cc][4096][32]
    float*    U1p    = (float*)(USum + 2097152);  // [4 kz][4 img][4096][128] fp32
    float*    U2     = U1p + 8388608;             // [4][4096][128] fp32
    float*    YR     = U2 + 2097152;              // 4*4096 fp32

    dim3 blk(256);

    prep_weights<<<2320, blk, 0, stream>>>(enc_w, gcn_w, ro_w,
                                           WencF, WgcnS, WgcnD, WroQ, WroS);
    feats_to_hwc<<<dim3(64, 4, 4), blk, 0, stream>>>(feats, featsT);

    // encoder shared conv: 4 ci-quad partials (kz), K=576 each
    conv_mfma<<<dim3(32, 4, 4), blk, 0, stream>>>(
        nullptr, nullptr, nullptr, 0, featsT, WencF, U1p, 4, 8, 2);
    enc_obj_sum<<<1024, blk, 0, stream>>>(masks, enc_w, enc_b, U1p, Sa, USum);

    // 2 message-passing steps, fused 36-image conv + combine
    conv_mfma<<<dim3(32, 36, 1), blk, 0, stream>>>(
        Sa, WgcnD, Sb, 32, USum, WgcnS, U2, 4, 4, 4);
    combine_sum<<<1024, blk, 0, stream>>>(Sb, U2, gcn_b, USum);

    conv_mfma<<<dim3(32, 36, 1), blk, 0, stream>>>(
        Sb, WgcnD, Sa, 32, USum, WgcnS, U2, 4, 4, 4);
    combine_sum<<<1024, blk, 0, stream>>>(Sa, U2, gcn_b, USum);

    // readout (final states in Sa)
    ro_shared<<<2048, blk, 0, stream>>>(featsT, WroQ, YR);
    ro_obj<<<8192, blk, 0, stream>>>(Sa, WroS, ro_b, YR, out);
}

// Round 10
// 272.108 us; speedup vs baseline: 2.0519x; 1.0026x over previous
//
#include <hip/hip_runtime.h>
#include <math.h>

// B=4, O=8, C=256, HID=128, H=W=64, STEPS=2
// m97-style MFMA conv: acts+weights staged to LDS via global_load_lds (16B),
// both double-buffered, 1 barrier per 32-ci tap-chunk (round-6 measured-best:
// 837 TF on the gcn dispatch = the m97 plateau).
//   enc:  relu(conv(feats,Wf) [8 ci-chunk fp16 partials] + conv(mask,Wm) + b)
//   gcn:  relu(conv(s_i,W1-W2) [raw] + conv(Sum,W2) + b)  -- one 36-img dispatch
//   ro :  sigmoid(conv(feats,Wa) + conv(s,Wb) + b)        -- reg-resident weights
// Activations fp16 chunked HWC: x[img][cc][px][ci32], 4KB contiguous slabs.

typedef unsigned short ushort_t;
typedef _Float16 f16x8 __attribute__((ext_vector_type(8)));
typedef float f32x4 __attribute__((ext_vector_type(4)));

#define GLDS(gsrc, ldst)                                                      \
    __builtin_amdgcn_global_load_lds(                                         \
        (const __attribute__((address_space(1))) unsigned int*)(gsrc),        \
        (__attribute__((address_space(3))) unsigned int*)(ldst), 16, 0, 0)

__device__ __forceinline__ ushort_t f2h(float f) {
    _Float16 h = (_Float16)f;
    return *(ushort_t*)&h;
}
__device__ __forceinline__ float h2f(ushort_t u) {
    _Float16 h = *(_Float16*)&u;
    return (float)h;
}

// ---- weight packing: WencF[t][cc8][co128][ci32], WgcnS/D[t][cc4][co128][ci32]
// readout: WroQ[8cc][4q][9t][8k], WroS[4cc][4q][9t][8k]
__global__ __launch_bounds__(256) void prep_weights(
    const float* __restrict__ enc_w, const float* __restrict__ gcn_w,
    const float* __restrict__ ro_w,
    ushort_t* __restrict__ WencF, ushort_t* __restrict__ WgcnS,
    ushort_t* __restrict__ WgcnD, ushort_t* __restrict__ WroQ,
    ushort_t* __restrict__ WroS)
{
    int i = blockIdx.x * 256 + threadIdx.x;
    if (i < 294912) {
        int ci32 = i & 31, co = (i >> 5) & 127, tc = i >> 12;   // tc = t*8+cc
        int t = tc >> 3, cc = tc & 7, ci = cc * 32 + ci32;
        WencF[i] = f2h(enc_w[(co * 257 + ci) * 9 + t]);
    } else if (i < 442368) {
        int j = i - 294912;
        int ci32 = j & 31, co = (j >> 5) & 127, tc = j >> 12;   // t*4+cc
        int t = tc >> 2, cc = tc & 3, ci = cc * 32 + ci32;
        WgcnS[j] = f2h(gcn_w[(co * 256 + 128 + ci) * 9 + t]);
    } else if (i < 589824) {
        int j = i - 442368;
        int ci32 = j & 31, co = (j >> 5) & 127, tc = j >> 12;
        int t = tc >> 2, cc = tc & 3, ci = cc * 32 + ci32;
        WgcnD[j] = f2h(gcn_w[(co * 256 + ci) * 9 + t] - gcn_w[(co * 256 + 128 + ci) * 9 + t]);
    } else if (i < 592128) {          // WroQ: 2304
        int j = i - 589824;
        int k = j & 7, r = j >> 3;
        int t = r % 9, cq = r / 9, q = cq & 3, cc = cq >> 2;
        WroQ[j] = f2h(ro_w[(cc * 32 + q * 8 + k) * 9 + t]);
    } else if (i < 593280) {          // WroS: 1152
        int j = i - 592128;
        int k = j & 7, r = j >> 3;
        int t = r % 9, cq = r / 9, q = cq & 3, cc = cq >> 2;
        WroS[j] = f2h(ro_w[(256 + cc * 32 + q * 8 + k) * 9 + t]);
    }
}

// ---- feats fp32 CHW -> fp16 chunked HWC [4][cc8][4096][32]
__global__ __launch_bounds__(256) void feats_to_hwc(const float* __restrict__ feats,
                                                    ushort_t* __restrict__ featsT)
{
    __shared__ float tile[64][65];
    int img = blockIdx.z, ct = blockIdx.y, pt = blockIdx.x;   // pt = row
    int t = threadIdx.x;
    int px_l = t & 63;
    const float* src = feats + ((size_t)img * 256 + ct * 64) * 4096 + pt * 64;
#pragma unroll
    for (int j = 0; j < 16; ++j) {
        int ci_l = (t >> 6) + j * 4;
        tile[px_l][ci_l] = src[(size_t)ci_l * 4096 + px_l];
    }
    __syncthreads();
    int px = t >> 2;
#pragma unroll
    for (int j = 0; j < 2; ++j) {
        int c8 = ((t & 3) + j * 4) * 8;
        uint4 v; ushort_t* pv = (ushort_t*)&v;
#pragma unroll
        for (int k = 0; k < 8; ++k) pv[k] = f2h(tile[px][c8 + k]);
        int cc = ct * 2 + (c8 >> 5);
        *(uint4*)(featsT + ((size_t)img * 8 + cc) * 131072 +
                  (size_t)(pt * 64 + px) * 32 + (c8 & 31)) = v;
    }
}

// ---- main conv (round-6 structure). grid (32 rowpairs, nA+nB imgs, kz).
// Block: 128 co x 128 px (2 rows), 4 waves (cg,pg); wave: 64 co x 64 px.
// A out: fp16 chunked raw at slot (kz*nA+img). B out: fp32 [px][128] raw.
__global__ __launch_bounds__(256, 3) void conv_mfma(
    const ushort_t* __restrict__ xA, const ushort_t* __restrict__ WA,
    ushort_t* __restrict__ outA, int nA,
    const ushort_t* __restrict__ xB, const ushort_t* __restrict__ WB,
    float* __restrict__ outB, int nB,
    int ncc_img, int ncc_blk)
{
    __shared__ ushort_t raw[25088];           // 50176 B
    ushort_t* xs = raw;                       // 2 x [4 rows][66 cols][32ci]
    ushort_t* wlds = raw + 16896;             // 2 x [128 co][32ci]
    ushort_t* eb16 = raw;                     // epilogue overlay [64][136]
    float* eb32 = (float*)raw;                // epilogue overlay [64][68]

    const int rp = blockIdx.x, img = blockIdx.y, kz = blockIdx.z;
    const int row0 = rp * 2;
    const int cc0 = kz * ncc_blk;
    const int nchunk = 9 * ncc_blk;
    const int tid = threadIdx.x;
    const int w = tid >> 6, lane = tid & 63, lq = lane >> 4, lr = lane & 15;
    const int cg = w >> 1, pg = w & 1;

    const bool isA = img < nA;
    const ushort_t* x = isA ? xA + (size_t)img * ncc_img * 131072
                            : xB + (size_t)(img - nA) * ncc_img * 131072;
    const ushort_t* W = isA ? WA : WB;

    const int aoff0 = (cg * 64 + lr) * 32 + lq * 8;

    // zero halo columns (0 and 65) of both act buffers, once
    if (tid < 64) {
        int b = tid >> 5, r = (tid >> 3) & 3, c = (tid >> 2) & 1, s = tid & 3;
        *(uint4*)(xs + b * 8448 + r * 2112 + (c ? 65 : 0) * 32 + s * 8) =
            make_uint4(0, 0, 0, 0);
    }

    f32x4 acc[4][4];
#pragma unroll
    for (int a = 0; a < 4; ++a)
#pragma unroll
        for (int p = 0; p < 4; ++p) acc[a][p] = (f32x4){0.f, 0.f, 0.f, 0.f};

    const int gy = row0 - 1 + w;
    const bool row_ok = (unsigned)gy < 64u;
#define STAGE_ACT(cc_, buf_)                                                    \
    {                                                                           \
        ushort_t* dst = xs + (buf_) * 8448 + w * 2112 + 32;                     \
        if (row_ok) {                                                           \
            const ushort_t* src = x + (size_t)(cc_) * 131072 + (size_t)gy * 2048; \
            GLDS(src + 0 * 512 + lane * 8, dst + 0 * 512);                      \
            GLDS(src + 1 * 512 + lane * 8, dst + 1 * 512);                      \
            GLDS(src + 2 * 512 + lane * 8, dst + 2 * 512);                      \
            GLDS(src + 3 * 512 + lane * 8, dst + 3 * 512);                      \
        } else {                                                                \
            *(uint4*)(dst + 0 * 512 + lane * 8) = make_uint4(0, 0, 0, 0);       \
            *(uint4*)(dst + 1 * 512 + lane * 8) = make_uint4(0, 0, 0, 0);       \
            *(uint4*)(dst + 2 * 512 + lane * 8) = make_uint4(0, 0, 0, 0);       \
            *(uint4*)(dst + 3 * 512 + lane * 8) = make_uint4(0, 0, 0, 0);       \
        }                                                                       \
    }
#define STAGE_W(t_, cc_, buf_)                                                  \
    {                                                                           \
        const ushort_t* src = W + ((size_t)((t_) * ncc_img + (cc_)) * 4096);    \
        ushort_t* dst = wlds + (buf_) * 4096;                                   \
        GLDS(src + (w * 2 + 0) * 512 + lane * 8, dst + (w * 2 + 0) * 512);      \
        GLDS(src + (w * 2 + 1) * 512 + lane * 8, dst + (w * 2 + 1) * 512);      \
    }

    STAGE_ACT(cc0, 0);
    STAGE_W(0, cc0, 0);

    int kc = 0;
    for (int ccl = 0; ccl < ncc_blk; ++ccl) {
        const int cc = cc0 + ccl;
        const int xb = ccl & 1;
#pragma unroll
        for (int t = 0; t < 9; ++t, ++kc) {
            __syncthreads();                  // drains glds issued last phase
            if (kc + 1 < nchunk) {
                if (t == 8) {
                    STAGE_W(0, cc + 1, (kc + 1) & 1);
                    STAGE_ACT(cc + 1, (ccl + 1) & 1);
                } else {
                    STAGE_W(t + 1, cc, (kc + 1) & 1);
                }
            }
            const int dy = t / 3, dx = t - 3 * dy;
            const ushort_t* wl = wlds + (kc & 1) * 4096 + aoff0;
            const ushort_t* xl = xs + xb * 8448 + (pg + dy) * 2112 + (dx + lr) * 32 + lq * 8;
            f16x8 A0 = *(const f16x8*)(wl);
            f16x8 A1 = *(const f16x8*)(wl + 512);    // +16 co
            f16x8 A2 = *(const f16x8*)(wl + 1024);
            f16x8 A3 = *(const f16x8*)(wl + 1536);
#pragma unroll
            for (int p = 0; p < 4; ++p) {
                f16x8 Bf = *(const f16x8*)(xl + p * 512);   // +16 px
                acc[0][p] = __builtin_amdgcn_mfma_f32_16x16x32_f16(A0, Bf, acc[0][p], 0, 0, 0);
                acc[1][p] = __builtin_amdgcn_mfma_f32_16x16x32_f16(A1, Bf, acc[1][p], 0, 0, 0);
                acc[2][p] = __builtin_amdgcn_mfma_f32_16x16x32_f16(A2, Bf, acc[2][p], 0, 0, 0);
                acc[3][p] = __builtin_amdgcn_mfma_f32_16x16x32_f16(A3, Bf, acc[3][p], 0, 0, 0);
            }
        }
    }

    // ---- epilogue (raw). A: fp16 chunked at slot kz*nA+img. B: fp32 [px][128].
    if (isA) {
        ushort_t* obase = outA + (size_t)(kz * nA + img) * 524288;   // 4cc x 131072
#pragma unroll
        for (int r = 0; r < 2; ++r) {
            __syncthreads();
            if (pg == r) {
#pragma unroll
                for (int cf = 0; cf < 4; ++cf)
#pragma unroll
                    for (int pf = 0; pf < 4; ++pf) {
                        int px = pf * 16 + lr;
                        int co_l = cg * 64 + cf * 16 + lq * 4;
                        ushort_t pk[4];
#pragma unroll
                        for (int j = 0; j < 4; ++j) pk[j] = f2h(acc[cf][pf][j]);
                        *(uint2*)(eb16 + px * 136 + co_l) = *(uint2*)pk;
                    }
            }
            __syncthreads();
#pragma unroll
            for (int k = 0; k < 4; ++k) {
                int i = tid + k * 256;
                int px = i >> 4, c16 = i & 15;
                uint4 v = *(uint4*)(eb16 + px * 136 + c16 * 8);
                *(uint4*)(obase + (size_t)(c16 >> 2) * 131072 +
                          (size_t)((row0 + r) * 64 + px) * 32 + (c16 & 3) * 8) = v;
            }
        }
    } else {
        float* obase = outB + ((size_t)kz * nB + (img - nA)) * 524288;
#pragma unroll
        for (int r = 0; r < 2; ++r)
#pragma unroll
            for (int h = 0; h < 2; ++h) {
                __syncthreads();
                if (pg == r && cg == h) {
#pragma unroll
                    for (int cf = 0; cf < 4; ++cf)
#pragma unroll
                        for (int pf = 0; pf < 4; ++pf)
                            *(f32x4*)(eb32 + (pf * 16 + lr) * 68 + cf * 16 + lq * 4) =
                                acc[cf][pf];
                }
                __syncthreads();
                for (int i = tid; i < 512; i += 256) {
                    int px = i >> 3, cl = (i & 7) * 8;
                    f32x4 v0 = *(f32x4*)(eb32 + px * 68 + cl);
                    f32x4 v1 = *(f32x4*)(eb32 + px * 68 + cl + 4);
                    float* op = obase + (size_t)((row0 + r) * 64 + px) * 128 + h * 64 + cl;
                    *(f32x4*)op = v0;
                    *(f32x4*)(op + 4) = v1;
                }
            }
    }
#undef STAGE_ACT
#undef STAGE_W
}

// ---- gcn combine: S = relu(S_raw + U2[b] + gcn_b), USum = sum_o S (chunked io)
__global__ __launch_bounds__(256) void combine_sum(
    ushort_t* __restrict__ S, const float* __restrict__ U2,
    const float* __restrict__ gcn_b, ushort_t* __restrict__ USum)
{
    int i = blockIdx.x * 256 + threadIdx.x;   // b(2)|px(12)|c16(4)
    int c8 = i & 15, px = (i >> 4) & 4095, b = i >> 16;
    int co = c8 * 8;
    size_t coff = (size_t)(c8 >> 2) * 131072 + (size_t)px * 32 + (c8 & 3) * 8;
    const float* u = U2 + ((size_t)b * 4096 + px) * 128 + co;
    float base[8];
#pragma unroll
    for (int k = 0; k < 8; ++k) base[k] = u[k] + gcn_b[co + k];
    float s[8] = {0, 0, 0, 0, 0, 0, 0, 0};
#pragma unroll
    for (int o = 0; o < 8; ++o) {
        ushort_t* p = S + (size_t)(b * 8 + o) * 524288 + coff;
        uint4 v = *(uint4*)p;
        ushort_t* vp = (ushort_t*)&v;
        uint4 sv; ushort_t* sp = (ushort_t*)&sv;
#pragma unroll
        for (int k = 0; k < 8; ++k) {
            float f = fmaxf(h2f(vp[k]) + base[k], 0.f);
            s[k] += f;
            sp[k] = f2h(f);
        }
        *(uint4*)p = sv;
    }
    uint4 sv; ushort_t* sp = (ushort_t*)&sv;
#pragma unroll
    for (int k = 0; k < 8; ++k) sp[k] = f2h(s[k]);
    *(uint4*)(USum + (size_t)b * 524288 + coff) = sv;
}

// ---- encoder per-object part + object-sum (8 fp16 chunked partials in)
__global__ __launch_bounds__(256) void enc_obj_sum(
    const float* __restrict__ masks, const float* __restrict__ enc_w,
    const float* __restrict__ enc_b, const ushort_t* __restrict__ U1p,
    ushort_t* __restrict__ S, ushort_t* __restrict__ USum)
{
    int i = blockIdx.x * 256 + threadIdx.x;   // b(2)|px(12)|c16(4)
    int c8 = i & 15, px = (i >> 4) & 4095, b = i >> 16;
    int co = c8 * 8;
    int y = px >> 6, xx = px & 63;
    size_t coff = (size_t)(c8 >> 2) * 131072 + (size_t)px * 32 + (c8 & 3) * 8;
    float base[8];
#pragma unroll
    for (int k = 0; k < 8; ++k) base[k] = enc_b[co + k];
#pragma unroll
    for (int p = 0; p < 8; ++p) {
        uint4 v = *(const uint4*)(U1p + (size_t)(p * 4 + b) * 524288 + coff);
        const ushort_t* vp = (const ushort_t*)&v;
#pragma unroll
        for (int k = 0; k < 8; ++k) base[k] += h2f(vp[k]);
    }
    float wm[8][9];
#pragma unroll
    for (int k = 0; k < 8; ++k) {
        const float* wp = enc_w + (size_t)((co + k) * 257 + 256) * 9;
#pragma unroll
        for (int t = 0; t < 9; ++t) wm[k][t] = wp[t];
    }
    float s[8] = {0, 0, 0, 0, 0, 0, 0, 0};
#pragma unroll
    for (int o = 0; o < 8; ++o) {
        const float* m = masks + (size_t)(b * 8 + o) * 4096;
        float mt[9];
#pragma unroll
        for (int dy = 0; dy < 3; ++dy)
#pragma unroll
            for (int dx = 0; dx < 3; ++dx) {
                int gy_ = y + dy - 1, gx = xx + dx - 1;
                mt[dy * 3 + dx] =
                    ((unsigned)gy_ < 64u && (unsigned)gx < 64u) ? m[gy_ * 64 + gx] : 0.f;
            }
        uint4 sv; ushort_t* sp = (ushort_t*)&sv;
#pragma unroll
        for (int k = 0; k < 8; ++k) {
            float acc = base[k];
#pragma unroll
            for (int t = 0; t < 9; ++t) acc = fmaf(mt[t], wm[k][t], acc);
            acc = fmaxf(acc, 0.f);
            s[k] += acc;
            sp[k] = f2h(acc);
        }
        *(uint4*)(S + (size_t)(b * 8 + o) * 524288 + coff) = sv;
    }
    uint4 sv; ushort_t* sp = (ushort_t*)&sv;
#pragma unroll
    for (int k = 0; k < 8; ++k) sp[k] = f2h(s[k]);
    *(uint4*)(USum + (size_t)b * 524288 + coff) = sv;
}

// ---- readout shared part: thread = 8 ci x 9 taps, weights in regs
__global__ __launch_bounds__(256) void ro_shared(
    const ushort_t* __restrict__ featsT, const ushort_t* __restrict__ WroQ,
    float* __restrict__ YR)
{
    int i = blockIdx.x * 256 + threadIdx.x;   // b(2)|px(12)|cu(5)
    int cu = i & 31, px = (i >> 5) & 4095, b = i >> 17;
    int cc = cu >> 2, q = cu & 3;
    int y = px >> 6, xcol = px & 63;
    const ushort_t* wp = WroQ + (size_t)(cc * 4 + q) * 72;
    float wreg[9][8];
#pragma unroll
    for (int t = 0; t < 9; ++t) {
        uint4 wv = *(const uint4*)(wp + t * 8);
        const ushort_t* wq = (const ushort_t*)&wv;
#pragma unroll
        for (int k = 0; k < 8; ++k) wreg[t][k] = h2f(wq[k]);
    }
    const ushort_t* fb = featsT + (size_t)(b * 8 + cc) * 131072 + q * 8;
    float acc = 0.f;
#pragma unroll
    for (int dy = 0; dy < 3; ++dy) {
        int gy = y + dy - 1;
        if ((unsigned)gy >= 64u) continue;
#pragma unroll
        for (int dx = 0; dx < 3; ++dx) {
            int gx = xcol + dx - 1;
            if ((unsigned)gx >= 64u) continue;
            uint4 v = *(const uint4*)(fb + (size_t)(gy * 64 + gx) * 32);
            const ushort_t* vp = (const ushort_t*)&v;
#pragma unroll
            for (int k = 0; k < 8; ++k)
                acc = fmaf(h2f(vp[k]), wreg[dy * 3 + dx][k], acc);
        }
    }
#pragma unroll
    for (int d = 16; d >= 1; d >>= 1) acc += __shfl_down(acc, d, 32);
    if (cu == 0) YR[b * 4096 + px] = acc;
}

// ---- readout per-object part: thread = 8 ci x 9 taps + sigmoid
__global__ __launch_bounds__(256) void ro_obj(
    const ushort_t* __restrict__ S, const ushort_t* __restrict__ WroS,
    const float* __restrict__ ro_b, const float* __restrict__ YR,
    float* __restrict__ out)
{
    int i = blockIdx.x * 256 + threadIdx.x;   // n(5)|px(12)|cu(4)
    int cu = i & 15, px = (i >> 4) & 4095, n = i >> 16;
    int b = n >> 3;
    int cc = cu >> 2, q = cu & 3;
    int y = px >> 6, xcol = px & 63;
    const ushort_t* wp = WroS + (size_t)(cc * 4 + q) * 72;
    float wreg[9][8];
#pragma unroll
    for (int t = 0; t < 9; ++t) {
        uint4 wv = *(const uint4*)(wp + t * 8);
        const ushort_t* wq = (const ushort_t*)&wv;
#pragma unroll
        for (int k = 0; k < 8; ++k) wreg[t][k] = h2f(wq[k]);
    }
    const ushort_t* sb = S + ((size_t)n * 4 + cc) * 131072 + q * 8;
    float acc = 0.f;
#pragma unroll
    for (int dy = 0; dy < 3; ++dy) {
        int gy = y + dy - 1;
        if ((unsigned)gy >= 64u) continue;
#pragma unroll
        for (int dx = 0; dx < 3; ++dx) {
            int gx = xcol + dx - 1;
            if ((unsigned)gx >= 64u) continue;
            uint4 v = *(const uint4*)(sb + (size_t)(gy * 64 + gx) * 32);
            const ushort_t* vp = (const ushort_t*)&v;
#pragma unroll
            for (int k = 0; k < 8; ++k)
                acc = fmaf(h2f(vp[k]), wreg[dy * 3 + dx][k], acc);
        }
    }
#pragma unroll
    for (int d = 8; d >= 1; d >>= 1) acc += __shfl_down(acc, d, 16);
    if (cu == 0) {
        float v = acc + YR[b * 4096 + px] + ro_b[0];
        out[n * 4096 + px] = 1.f / (1.f + __expf(-v));
    }
}

extern "C" void kernel_launch(void* const* d_in, const int* in_sizes, int n_in,
                              void* d_out, int out_size, void* d_ws, size_t ws_size,
                              hipStream_t stream)
{
    const float* feats = (const float*)d_in[0];   // [4,256,64,64]
    const float* masks = (const float*)d_in[1];   // [4,8,64,64]
    const float* enc_w = (const float*)d_in[4];   // [128,257,3,3]
    const float* enc_b = (const float*)d_in[5];
    const float* gcn_w = (const float*)d_in[6];   // [128,256,3,3]
    const float* gcn_b = (const float*)d_in[7];
    const float* ro_w  = (const float*)d_in[8];   // [1,384,3,3]
    const float* ro_b  = (const float*)d_in[9];
    float* out = (float*)d_out;                   // [4,8,64,64]

    // workspace: fp16 region then fp32 region (16B-aligned)
    ushort_t* WencF  = (ushort_t*)d_ws;           // 294912
    ushort_t* WgcnS  = WencF + 294912;            // 147456
    ushort_t* WgcnD  = WgcnS + 147456;            // 147456
    ushort_t* WroQ   = WgcnD + 147456;            // 2304
    ushort_t* WroS   = WroQ + 2304;               // 1152
    ushort_t* featsT = WroS + 1152;               // [4][8cc][4096][32]
    ushort_t* Sa     = featsT + 4194304;          // [32][4cc][4096][32]
    ushort_t* Sb     = Sa + 16777216;
    ushort_t* USum   = Sb + 16777216;             // [4][4cc][4096][32]
    ushort_t* U1p16  = USum + 2097152;            // [8 kz][4 img][4cc][4096][32] fp16
    float*    U2     = (float*)(U1p16 + 16777216);// [4][4096][128] fp32
    float*    YR     = U2 + 2097152;              // 4*4096 fp32

    dim3 blk(256);

    prep_weights<<<2320, blk, 0, stream>>>(enc_w, gcn_w, ro_w,
                                           WencF, WgcnS, WgcnD, WroQ, WroS);
    feats_to_hwc<<<dim3(64, 4, 4), blk, 0, stream>>>(feats, featsT);

    // encoder shared conv: 8 ci-chunk fp16 partials (kz), K=288 each, 1024 blocks
    conv_mfma<<<dim3(32, 4, 8), blk, 0, stream>>>(
        featsT, WencF, U1p16, 4, nullptr, nullptr, nullptr, 0, 8, 1);
    enc_obj_sum<<<1024, blk, 0, stream>>>(masks, enc_w, enc_b, U1p16, Sa, USum);

    // 2 message-passing steps, fused 36-image conv + combine
    conv_mfma<<<dim3(32, 36, 1), blk, 0, stream>>>(
        Sa, WgcnD, Sb, 32, USum, WgcnS, U2, 4, 4, 4);
    combine_sum<<<1024, blk, 0, stream>>>(Sb, U2, gcn_b, USum);

    conv_mfma<<<dim3(32, 36, 1), blk, 0, stream>>>(
        Sb, WgcnD, Sa, 32, USum, WgcnS, U2, 4, 4, 4);
    combine_sum<<<1024, blk, 0, stream>>>(Sa, U2, gcn_b, USum);

    // readout (final states in Sa)
    ro_shared<<<2048, blk, 0, stream>>>(featsT, WroQ, YR);
    ro_obj<<<8192, blk, 0, stream>>>(Sa, WroS, ro_b, YR, out);
}